// Round 7
// baseline (230.517 us; speedup 1.0000x reference)
//
#include <hip/hip_runtime.h>
#include <math.h>

#define LN 4096
#define CN 64
#define NTH 256

// ws offsets (floats)
#define OFF_CHAN_SUM    0        // 2048
#define OFF_CHAN_JERK   2048     // 2048
#define OFF_CHAN_JRATE  4096     // 2048
#define OFF_CHAN_ZCR    6144     // 2048
#define OFF_SVMST_PART  8192     // 32 b * 32 chunks * 8 = 8192
#define OFF_SPEC_PART   16384    // 1024 * 3
#define OFF_GNP         19584    // 2048 double pairs (byte 78336 % 8 == 0)
#define OFF_SVMBUF      27776    // 32 * 4096
#define OFF_MIX         158848   // bf16 mixed: 32*64*4096 ushorts = 4194304 floats
// total ~4.35M floats = 17.4 MB (< ws)

#define FP(i) ((i) + ((i) >> 4))

__device__ __forceinline__ unsigned short f2bf(float f) {
  unsigned u = __float_as_uint(f);
  unsigned r = (u + 0x7FFFu + ((u >> 16) & 1u)) >> 16;
  return (unsigned short)r;
}

// radix-4 DIT butterfly in place; twiddles applied to b,c,d
__device__ __forceinline__ void bfly4(float2& a, float2& b, float2& c, float2& d,
                                      float w1r, float w1i, float w2r, float w2i,
                                      float w3r, float w3i) {
  float t1r = b.x*w1r - b.y*w1i, t1i = b.x*w1i + b.y*w1r;
  float t2r = c.x*w2r - c.y*w2i, t2i = c.x*w2i + c.y*w2r;
  float t3r = d.x*w3r - d.y*w3i, t3i = d.x*w3i + d.y*w3r;
  float ar = a.x + t2r, ai = a.y + t2i;
  float br = a.x - t2r, bi = a.y - t2i;
  float cr = t1r + t3r, ci = t1i + t3i;
  float dr = t1r - t3r, di = t1i - t3i;
  a = make_float2(ar + cr, ai + ci);
  b = make_float2(br + di, bi - dr);
  c = make_float2(ar - cr, ai - ci);
  d = make_float2(br - di, bi + dr);
}

__device__ __forceinline__ float4 ldmask(const float* __restrict__ row, int idx) {
  int idxc = idx < 0 ? 0 : (idx > LN - 4 ? LN - 4 : idx);
  float4 v = *(const float4*)(row + idxc);
  float m = (idx == idxc) ? 1.f : 0.f;
  v.x *= m; v.y *= m; v.z *= m; v.w *= m;
  return v;
}

#define F16(wv,a0,a1,a2,a3,a4,a5,a6,a7,a8,a9,aA,aB,aC,aD,aE,aF) \
  acc[0]=fmaf(wv,a0,acc[0]);  acc[1]=fmaf(wv,a1,acc[1]);  acc[2]=fmaf(wv,a2,acc[2]);  acc[3]=fmaf(wv,a3,acc[3]);  \
  acc[4]=fmaf(wv,a4,acc[4]);  acc[5]=fmaf(wv,a5,acc[5]);  acc[6]=fmaf(wv,a6,acc[6]);  acc[7]=fmaf(wv,a7,acc[7]);  \
  acc[8]=fmaf(wv,a8,acc[8]);  acc[9]=fmaf(wv,a9,acc[9]);  acc[10]=fmaf(wv,aA,acc[10]); acc[11]=fmaf(wv,aB,acc[11]); \
  acc[12]=fmaf(wv,aC,acc[12]); acc[13]=fmaf(wv,aD,acc[13]); acc[14]=fmaf(wv,aE,acc[14]); acc[15]=fmaf(wv,aF,acc[15]);

// ================= k1: svm slice + FFT (2 real ch packed) + fused row scans =================
__global__ __launch_bounds__(NTH) void k1_spec(const float* __restrict__ x, float* __restrict__ ws) {
  __shared__ __align__(16) char smraw[35072];
  int i = blockIdx.x;
  int b = i >> 5, sl = i & 31;   // 32 batches x 32 slots
  int t = threadIdx.x;

  // ---- P1a: svm slice (128 l per block, all 64 channels) ----
  {
    float* tmp = (float*)smraw;                       // 128 floats
    float (*sred)[8] = (float(*)[8])(smraw + 512);    // [2][8]
    int lt = t & 127, ch = t >> 7;
    int l = sl * 128 + lt;
    const float* xb = x + (size_t)b * CN * LN + l;
    float acc = 0.f;
#pragma unroll
    for (int cc = 0; cc < 32; cc++) {
      float v = xb[(size_t)(ch * 32 + cc) * LN];
      acc = fmaf(v, v, acc);
    }
    if (ch == 1) tmp[lt] = acc;
    __syncthreads();
    if (ch == 0) {
      acc += tmp[lt];
      float svm = sqrtf(acc);
      ws[OFF_SVMBUF + (size_t)b * LN + l] = svm;
      const int third = LN / 3;     // 1365
      float vS = svm, vS2 = svm * svm;
      float vS2H  = (l >= LN/2) ? svm : 0.f;
      float vS2H2 = (l >= LN/2) ? svm * svm : 0.f;
      float vPRE  = (l < third) ? svm : 0.f;
      float vPOST = (l >= 2*third) ? svm : 0.f;
      float vMX = svm;
      float vMID = (l >= third && l < 2*third) ? svm : 0.f;
      for (int off = 32; off > 0; off >>= 1) {
        vS += __shfl_down(vS, off); vS2 += __shfl_down(vS2, off);
        vS2H += __shfl_down(vS2H, off); vS2H2 += __shfl_down(vS2H2, off);
        vPRE += __shfl_down(vPRE, off); vPOST += __shfl_down(vPOST, off);
        vMX = fmaxf(vMX, __shfl_down(vMX, off));
        vMID = fmaxf(vMID, __shfl_down(vMID, off));
      }
      if ((t & 63) == 0) {
        int w = t >> 6;
        sred[w][0]=vS; sred[w][1]=vS2; sred[w][2]=vMX; sred[w][3]=vS2H;
        sred[w][4]=vS2H2; sred[w][5]=vPRE; sred[w][6]=vMID; sred[w][7]=vPOST;
      }
    }
    __syncthreads();
    if (t == 0) {
      float* sp = ws + OFF_SVMST_PART + (size_t)(b * 32 + sl) * 8;
      sp[0]=sred[0][0]+sred[1][0];
      sp[1]=sred[0][1]+sred[1][1];
      sp[2]=fmaxf(sred[0][2],sred[1][2]);
      sp[3]=sred[0][3]+sred[1][3];
      sp[4]=sred[0][4]+sred[1][4];
      sp[5]=sred[0][5]+sred[1][5];
      sp[6]=fmaxf(sred[0][6],sred[1][6]);
      sp[7]=sred[0][7]+sred[1][7];
    }
    __syncthreads();   // before FFT overwrites smraw
  }

  // ---- P1b: FFT + fused row scans ----
  {
    const float* r0 = x + ((size_t)b * CN + 2 * sl) * LN;
    const float* r1 = r0 + LN;
    float2* z = (float2*)smraw;                        // FP(4096) float2 < 34816 B
    float (*sred8)[8] = (float(*)[8])(smraw + 34816);  // [4][8] scan partials
    float s0 = 0.f, jm0 = 0.f, jr0 = 0.f; int zc0 = 0;
    float s1v = 0.f, jm1 = 0.f, jr1 = 0.f; int zc1 = 0;
#pragma unroll
    for (int k = 0; k < 4; k++) {
      int n4 = (k * 256 + t) * 4;
      float4 a = *(const float4*)(r0 + n4);
      float4 c = *(const float4*)(r1 + n4);
      float a4 = __shfl_down(a.x, 1), a5 = __shfl_down(a.y, 1);
      float c4 = __shfl_down(c.x, 1), c5 = __shfl_down(c.y, 1);
      if ((t & 63) == 63) {
        a4 = (n4 + 4 < LN) ? r0[n4 + 4] : 0.f;
        a5 = (n4 + 5 < LN) ? r0[n4 + 5] : 0.f;
        c4 = (n4 + 4 < LN) ? r1[n4 + 4] : 0.f;
        c5 = (n4 + 5 < LN) ? r1[n4 + 5] : 0.f;
      }
      bool nl = (n4 + 4 < LN);
      s0 += a.x + a.y + a.z + a.w;
      jm0 = fmaxf(jm0, fmaxf(fmaxf(fabsf(a.y-a.x), fabsf(a.z-a.y)), fabsf(a.w-a.z)));
      zc0 += (a.x*a.y < 0.f) + (a.y*a.z < 0.f) + (a.z*a.w < 0.f);
      jr0 = fmaxf(jr0, fmaxf(fabsf(a.z - 2.f*a.y + a.x), fabsf(a.w - 2.f*a.z + a.y)));
      if (nl) {
        jm0 = fmaxf(jm0, fabsf(a4 - a.w));
        zc0 += (a.w * a4 < 0.f);
        jr0 = fmaxf(jr0, fmaxf(fabsf(a4 - 2.f*a.w + a.z), fabsf(a5 - 2.f*a4 + a.w)));
      }
      s1v += c.x + c.y + c.z + c.w;
      jm1 = fmaxf(jm1, fmaxf(fmaxf(fabsf(c.y-c.x), fabsf(c.z-c.y)), fabsf(c.w-c.z)));
      zc1 += (c.x*c.y < 0.f) + (c.y*c.z < 0.f) + (c.z*c.w < 0.f);
      jr1 = fmaxf(jr1, fmaxf(fabsf(c.z - 2.f*c.y + c.x), fabsf(c.w - 2.f*c.z + c.y)));
      if (nl) {
        jm1 = fmaxf(jm1, fabsf(c4 - c.w));
        zc1 += (c.w * c4 < 0.f);
        jr1 = fmaxf(jr1, fmaxf(fabsf(c4 - 2.f*c.w + c.z), fabsf(c5 - 2.f*c4 + c.w)));
      }
      float ar[4] = {a.x, a.y, a.z, a.w}, crr[4] = {c.x, c.y, c.z, c.w};
#pragma unroll
      for (int q = 0; q < 4; q++) {
        unsigned n = (unsigned)(n4 + q);
        unsigned br = __brev(n) >> 20;
        unsigned dr = ((br & 0x555u) << 1) | ((br & 0xAAAu) >> 1);
        z[FP(dr)] = make_float2(ar[q], crr[q]);
      }
    }
    for (int off = 32; off > 0; off >>= 1) {
      s0 += __shfl_down(s0, off); jm0 = fmaxf(jm0, __shfl_down(jm0, off));
      jr0 = fmaxf(jr0, __shfl_down(jr0, off)); zc0 += __shfl_down(zc0, off);
      s1v += __shfl_down(s1v, off); jm1 = fmaxf(jm1, __shfl_down(jm1, off));
      jr1 = fmaxf(jr1, __shfl_down(jr1, off)); zc1 += __shfl_down(zc1, off);
    }
    if ((t & 63) == 0) {
      int w = t >> 6;
      sred8[w][0]=s0; sred8[w][1]=jm0; sred8[w][2]=jr0; sred8[w][3]=(float)zc0;
      sred8[w][4]=s1v; sred8[w][5]=jm1; sred8[w][6]=jr1; sred8[w][7]=(float)zc1;
    }
    __syncthreads();
    if (t == 0) {
      int bc0 = b * CN + 2 * sl;
      float S0=0,J0=0,JR0=0,Z0=0,S1=0,J1=0,JR1=0,Z1=0;
      for (int w = 0; w < 4; w++) {
        S0 += sred8[w][0]; J0 = fmaxf(J0, sred8[w][1]); JR0 = fmaxf(JR0, sred8[w][2]); Z0 += sred8[w][3];
        S1 += sred8[w][4]; J1 = fmaxf(J1, sred8[w][5]); JR1 = fmaxf(JR1, sred8[w][6]); Z1 += sred8[w][7];
      }
      ws[OFF_CHAN_SUM + bc0]       = S0;           ws[OFF_CHAN_SUM + bc0 + 1]   = S1;
      ws[OFF_CHAN_JERK + bc0]      = J0 * 50.f;    ws[OFF_CHAN_JERK + bc0 + 1]  = J1 * 50.f;
      ws[OFF_CHAN_JRATE + bc0]     = JR0 * 2500.f; ws[OFF_CHAN_JRATE + bc0 + 1] = JR1 * 2500.f;
      ws[OFF_CHAN_ZCR + bc0]       = Z0;           ws[OFF_CHAN_ZCR + bc0 + 1]   = Z1;
    }
    const float c8r[4] = { 1.f, 0.92387953251f, 0.70710678119f, 0.38268343236f };
    const float c8i[4] = { 0.f, -0.38268343236f, -0.70710678119f, -0.92387953251f };
#pragma unroll
    for (int p = 0; p < 3; p++) {
      const int H = (p == 0) ? 1 : (p == 1) ? 16 : 256;
      int rr = t & (H - 1);
      int B = ((t / H) * 16 * H) + rr;
      float2 E[16];
#pragma unroll
      for (int q = 0; q < 16; q++) E[q] = z[FP(B + q * H)];
      float su, cu;
      sincospif((float)rr / (8.0f * (float)H), &su, &cu);
      float ur = cu, ui = -su;
      float u2r = ur*ur - ui*ui, u2i = 2.f*ur*ui;
      float w1r = u2r*u2r - u2i*u2i, w1i = 2.f*u2r*u2i;      // u^4
      float w2r = w1r*w1r - w1i*w1i, w2i = 2.f*w1r*w1i;       // u^8
      float w3r = w2r*w1r - w2i*w1i, w3i = w2r*w1i + w2i*w1r; // u^12
#pragma unroll
      for (int m = 0; m < 4; m++)
        bfly4(E[4*m], E[4*m+1], E[4*m+2], E[4*m+3], w1r, w1i, w2r, w2i, w3r, w3i);
#pragma unroll
      for (int m = 0; m < 4; m++) {
        float W1r = ur*c8r[m] - ui*c8i[m];
        float W1i = ur*c8i[m] + ui*c8r[m];
        float W2r = W1r*W1r - W1i*W1i, W2i = 2.f*W1r*W1i;
        float W3r = W2r*W1r - W2i*W1i, W3i = W2r*W1i + W2i*W1r;
        bfly4(E[m], E[m+4], E[m+8], E[m+12], W1r, W1i, W2r, W2i, W3r, W3i);
      }
#pragma unroll
      for (int q = 0; q < 16; q++) z[FP(B + q * H)] = E[q];
      __syncthreads();
    }
    float tot = 0.f, cen = 0.f, hi = 0.f;
    for (int k = t; k <= LN / 2; k += NTH) {
      float p;
      if (k == 0 || k == LN / 2) {
        float2 v = z[FP(k)];
        p = v.x * v.x + v.y * v.y;
      } else {
        float2 zk = z[FP(k)], zn = z[FP(LN - k)];
        float a1 = zk.x + zn.x, a2 = zk.y - zn.y, a3 = zk.y + zn.y, a4v = zk.x - zn.x;
        p = 0.25f * (a1*a1 + a2*a2 + a3*a3 + a4v*a4v);
      }
      p *= (1.0f / LN);
      tot += p;
      cen += p * ((float)k * (1.0f / (LN / 2)));
      if (k >= 820) hi += p;
    }
    for (int off = 32; off > 0; off >>= 1) {
      tot += __shfl_down(tot, off);
      cen += __shfl_down(cen, off);
      hi  += __shfl_down(hi, off);
    }
    float (*redS)[4] = (float(*)[4])(smraw + 34816);
    if ((t & 63) == 0) { int w = t >> 6; redS[0][w] = tot; redS[1][w] = cen; redS[2][w] = hi; }
    __syncthreads();
    if (t == 0) {
      float* sp = ws + OFF_SPEC_PART + (size_t)(b * 32 + sl) * 3;
      sp[0] = redS[0][0]+redS[0][1]+redS[0][2]+redS[0][3];
      sp[1] = redS[1][0]+redS[1][1]+redS[1][2]+redS[1][3];
      sp[2] = redS[2][0]+redS[2][1]+redS[2][2]+redS[2][3];
    }
  }
}

// ================= k2: round-2 gate + eff weights + conv (2 rows/block), bf16 mixed out =================
__global__ __launch_bounds__(NTH) void k2_conv(
    const float* __restrict__ x,
    const float* __restrict__ dw7, const float* __restrict__ dw15,
    const float* __restrict__ dw31, const float* __restrict__ dw63,
    const float* __restrict__ bn_g, const float* __restrict__ bn_b,
    const float* __restrict__ bn_m, const float* __restrict__ bn_v,
    const float* __restrict__ comp_w1, const float* __restrict__ comp_b1,
    const float* __restrict__ comp_w2, const float* __restrict__ comp_b2,
    const float* __restrict__ pn_g, const float* __restrict__ pn_b,
    const float* __restrict__ pn_m, const float* __restrict__ pn_v,
    const float* __restrict__ pe_w1, const float* __restrict__ pe_b1,
    const float* __restrict__ pe_w2, const float* __restrict__ pe_b2,
    const float* __restrict__ pg_w, const float* __restrict__ pg_b,
    const float* __restrict__ temperature,
    float* __restrict__ ws)
{
  int i = blockIdx.x;
  int b = i >> 5, sl = i & 31;
  int t = threadIdx.x;
  __shared__ float sp8[32][8];
  __shared__ float sp3[32][3];
  __shared__ float stv[10];
  __shared__ float bc2[2];
  __shared__ float xm[64], h[64], pf[12], pe1v[32], pe2v[32], lgts[4], swts[4];
  __shared__ int ri[3][4], cnts[3];
  __shared__ float cwt[2][64];
  __shared__ float cbias[2];
  __shared__ double rda[2][4];

  // ---- gate (round-2 structure, verbatim) ----
  if (t < 32) {
    const float* p = ws + OFF_SVMST_PART + (size_t)(b * 32 + t) * 8;
#pragma unroll
    for (int q = 0; q < 8; q++) sp8[t][q] = p[q];
  }
  if (t >= 32 && t < 64) {
    int q = t - 32;
    const float* p = ws + OFF_SPEC_PART + (size_t)(b * 32 + q) * 3;
    sp3[q][0] = p[0]; sp3[q][1] = p[1]; sp3[q][2] = p[2];
  }
  __syncthreads();
  if (t == 0) {
    float S=0,S2=0,MX=-1e30f,S2H=0,S2H2=0,PRE=0,MID=-1e30f,POST=0;
    for (int q = 0; q < 32; q++) {
      S += sp8[q][0]; S2 += sp8[q][1]; MX = fmaxf(MX, sp8[q][2]);
      S2H += sp8[q][3]; S2H2 += sp8[q][4]; PRE += sp8[q][5];
      MID = fmaxf(MID, sp8[q][6]); POST += sp8[q][7];
    }
    float tt=0,ce=0,hh=0;
    for (int q = 0; q < 32; q++) { tt += sp3[q][0]; ce += sp3[q][1]; hh += sp3[q][2]; }
    stv[0]=S; stv[1]=S2; stv[2]=MX; stv[3]=S2H; stv[4]=S2H2;
    stv[5]=PRE; stv[6]=MID; stv[7]=POST; stv[8]=ce/(tt+1e-6f); stv[9]=hh/(tt+1e-6f);
    float mean = S * (1.f / LN);
    float var = (S2 - S * S * (1.f / LN)) * (1.f / (LN - 1));
    var = fmaxf(var, 0.f);
    bc2[0] = mean;
    bc2[1] = sqrtf(var) + 1e-6f;
  }
  __syncthreads();
  float mean = bc2[0], stde = bc2[1];
  float thr2 = mean + 2.f * stde, thr3 = mean + 3.f * stde, thrf = mean - stde;
  const float* svm = ws + OFF_SVMBUF + (size_t)b * LN;
  int cc2 = 0, cc3 = 0, ccf = 0;
  for (int l = t; l < LN; l += NTH) {
    float v = svm[l];
    cc2 += (v > thr2); cc3 += (v > thr3); ccf += (v < thrf);
  }
  for (int off = 32; off > 0; off >>= 1) {
    cc2 += __shfl_down(cc2, off); cc3 += __shfl_down(cc3, off); ccf += __shfl_down(ccf, off);
  }
  {
    int w = t >> 6;
    if ((t & 63) == 0) { ri[0][w] = cc2; ri[1][w] = cc3; ri[2][w] = ccf; }
  }
  float j = 0.f, jr = 0.f, zz = 0.f;
  if (t < 64) {
    xm[t] = ws[OFF_CHAN_SUM + b * 64 + t] * (1.0f / LN);
    j  = ws[OFF_CHAN_JERK + b * 64 + t];
    jr = ws[OFF_CHAN_JRATE + b * 64 + t];
    zz = ws[OFF_CHAN_ZCR + b * 64 + t];
    for (int off = 32; off > 0; off >>= 1) {
      j += __shfl_down(j, off); jr += __shfl_down(jr, off); zz += __shfl_down(zz, off);
    }
  }
  __syncthreads();
  if (t == 0) {
    cnts[0] = ri[0][0]+ri[0][1]+ri[0][2]+ri[0][3];
    cnts[1] = ri[1][0]+ri[1][1]+ri[1][2]+ri[1][3];
    cnts[2] = ri[2][0]+ri[2][1]+ri[2][2]+ri[2][3];
    const int third = LN / 3;
    float S2H = stv[3], S2H2 = stv[4];
    float n2 = (float)(LN / 2);
    float var2 = (S2H2 - S2H * S2H / n2) / (n2 - 1.f);
    var2 = fmaxf(var2, 0.f);
    float post_still = tanhf(1.f / (sqrtf(var2) + 1e-6f));
    float pre_mean = stv[5] / (float)third;
    float post_mean = stv[7] / (float)(LN - 2 * third);
    float pk = stv[6];
    float fp2 = fmaxf(pk - pre_mean, 0.f) + fmaxf(pk - post_mean, 0.f);
    fp2 = fp2 / (fabsf(pk) + 1e-6f);
    pf[0] = stv[2];
    pf[1] = mean;
    pf[2] = j * (1.f / 64);
    pf[3] = jr * (1.f / 64);
    pf[4] = (zz * (1.f / 64)) * (1.f / LN);
    pf[5] = (float)cnts[0] / LN;
    pf[6] = (float)cnts[1] / LN;
    pf[7] = post_still;
    pf[8] = (float)cnts[2] / LN;
    pf[9] = stv[8];
    pf[10] = stv[9];
    pf[11] = fp2;
  }
  __syncthreads();
  if (t < 12) pf[t] = (pf[t] - pn_m[t]) * rsqrtf(pn_v[t] + 1e-5f) * pn_g[t] + pn_b[t];
  __syncthreads();
  if (t < 64) {
    float hv = comp_b1[t];
    for (int q = 0; q < 64; q++) hv = fmaf(xm[q], comp_w1[q * 64 + t], hv);
    h[t] = fmaxf(hv, 0.f);
  }
  if (t < 32) {
    float v = pe_b1[t];
    for (int q = 0; q < 12; q++) v = fmaf(pf[q], pe_w1[q * 32 + t], v);
    pe1v[t] = fmaxf(v, 0.f);
  }
  __syncthreads();
  if (t < 32) {
    float v = pe_b2[t];
    for (int q = 0; q < 32; q++) v = fmaf(pe1v[q], pe_w2[q * 32 + t], v);
    pe2v[t] = fmaxf(v, 0.f);
  }
  __syncthreads();
  if (t < 4) {
    float v = comp_b2[t];
    for (int q = 0; q < 64; q++) v = fmaf(h[q], comp_w2[q * 4 + t], v);
    float g = pg_b[t];
    for (int q = 0; q < 32; q++) g = fmaf(pe2v[q], pg_w[q * 4 + t], g);
    g = 1.f / (1.f + expf(-g));
    float temp = fmaxf(temperature[0], 0.1f);
    lgts[t] = v * g / temp;
  }
  __syncthreads();
  if (t < 4) {
    float m = fmaxf(fmaxf(lgts[0], lgts[1]), fmaxf(lgts[2], lgts[3]));
    float den = expf(lgts[0]-m) + expf(lgts[1]-m) + expf(lgts[2]-m) + expf(lgts[3]-m);
    swts[t] = expf(lgts[t] - m) / den;
  }
  __syncthreads();

  // ---- eff weights for this block's 2 channels ----
  if (t < 128) {
    int rr = t >> 6, tau = t & 63;
    int c = 2 * sl + rr;
    float w0 = swts[0], w1 = swts[1], w2 = swts[2], w3 = swts[3];
    float sc0 = bn_g[0*64+c] * rsqrtf(bn_v[0*64+c] + 1e-5f);
    float sc1 = bn_g[1*64+c] * rsqrtf(bn_v[1*64+c] + 1e-5f);
    float sc2 = bn_g[2*64+c] * rsqrtf(bn_v[2*64+c] + 1e-5f);
    float sc3 = bn_g[3*64+c] * rsqrtf(bn_v[3*64+c] + 1e-5f);
    float a0 = w0*sc0, a1 = w1*sc1, a2 = w2*sc2, a3 = w3*sc3;
    if (tau == 0) {
      float o0 = bn_b[0*64+c] - bn_m[0*64+c] * sc0;
      float o1 = bn_b[1*64+c] - bn_m[1*64+c] * sc1;
      float o2 = bn_b[2*64+c] - bn_m[2*64+c] * sc2;
      float o3 = bn_b[3*64+c] - bn_m[3*64+c] * sc3;
      cbias[rr] = w0*o0 + w1*o1 + w2*o2 + w3*o3;
    }
    float v = 0.f;
    if (tau < 63) {
      v = a3 * dw63[c * 63 + tau];
      int i7 = tau - 28;  if (i7 >= 0 && i7 < 7)    v = fmaf(a0, dw7[c * 7 + i7], v);
      int i15 = tau - 24; if (i15 >= 0 && i15 < 15) v = fmaf(a1, dw15[c * 15 + i15], v);
      int i31 = tau - 16; if (i31 >= 0 && i31 < 31) v = fmaf(a2, dw31[c * 31 + i31], v);
    }
    cwt[rr][tau] = v;
  }
  __syncthreads();

  // ---- conv: 2 rows, 5-register sliding window; bf16 output to ws ----
#pragma unroll 1
  for (int r = 0; r < 2; r++) {
    int c = 2 * sl + r;
    const float* row = x + ((size_t)b * CN + c) * LN;
    const float* wtp = cwt[r];
    float bias = cbias[r];
    int l0 = t * 16, g0 = l0 - 32;
    float4 R0 = ldmask(row, g0);
    float4 R1 = ldmask(row, g0 + 4);
    float4 R2 = ldmask(row, g0 + 8);
    float4 R3 = ldmask(row, g0 + 12);
    float4 R4 = ldmask(row, g0 + 16);
    float acc[16];
#pragma unroll
    for (int q = 0; q < 16; q++) acc[q] = bias;
#pragma unroll
    for (int g = 0; g < 16; g++) {
      float w0 = wtp[4*g], w1 = wtp[4*g+1], w2 = wtp[4*g+2], w3 = wtp[4*g+3];
      F16(w0, R0.y,R0.z,R0.w,R1.x,R1.y,R1.z,R1.w,R2.x,R2.y,R2.z,R2.w,R3.x,R3.y,R3.z,R3.w,R4.x)
      F16(w1, R0.z,R0.w,R1.x,R1.y,R1.z,R1.w,R2.x,R2.y,R2.z,R2.w,R3.x,R3.y,R3.z,R3.w,R4.x,R4.y)
      F16(w2, R0.w,R1.x,R1.y,R1.z,R1.w,R2.x,R2.y,R2.z,R2.w,R3.x,R3.y,R3.z,R3.w,R4.x,R4.y,R4.z)
      F16(w3, R1.x,R1.y,R1.z,R1.w,R2.x,R2.y,R2.z,R2.w,R3.x,R3.y,R3.z,R3.w,R4.x,R4.y,R4.z,R4.w)
      if (g < 15) {
        R0 = R1; R1 = R2; R2 = R3; R3 = R4;
        R4 = ldmask(row, g0 + 4 * (g + 5));
      }
    }
    double ls = 0, ls2 = 0;
#pragma unroll
    for (int q = 0; q < 16; q++) { float v = acc[q]; ls += v; ls2 += (double)v * (double)v; }
    for (int off = 32; off > 0; off >>= 1) {
      ls += __shfl_down(ls, off);
      ls2 += __shfl_down(ls2, off);
    }
    int w = t >> 6;
    if ((t & 63) == 0) { rda[0][w] = ls; rda[1][w] = ls2; }
    // bf16 pack: 16 values -> 8 u32 -> 2 uint4 stores (32 B/thread, contiguous)
    unsigned short* mdst = (unsigned short*)(ws + OFF_MIX) + ((size_t)(b * CN + c)) * LN + l0;
    unsigned pk[8];
#pragma unroll
    for (int q = 0; q < 8; q++)
      pk[q] = (unsigned)f2bf(acc[2*q]) | ((unsigned)f2bf(acc[2*q+1]) << 16);
    uint4 v0 = make_uint4(pk[0], pk[1], pk[2], pk[3]);
    uint4 v1 = make_uint4(pk[4], pk[5], pk[6], pk[7]);
    *(uint4*)(mdst) = v0;
    *(uint4*)(mdst + 8) = v1;
    __syncthreads();
    if (t == 0) {
      double* gp = (double*)(ws + OFF_GNP);
      gp[2 * (b * CN + c) + 0] = rda[0][0]+rda[0][1]+rda[0][2]+rda[0][3];
      gp[2 * (b * CN + c) + 1] = rda[1][0]+rda[1][1]+rda[1][2]+rda[1][3];
    }
    __syncthreads();
  }
}

// ================= k3: GN + GELU + proj + residual (2 x 64-l passes, bf16 mixed in) =================
__global__ __launch_bounds__(NTH) void k3_final(const float* __restrict__ x,
    const float* __restrict__ proj_w, const float* __restrict__ proj_b,
    const float* __restrict__ gn_g, const float* __restrict__ gn_b,
    const float* __restrict__ res_scale,
    const float* __restrict__ ws, float* out) {
  __shared__ __align__(16) char smraw[32840];
  int i = blockIdx.x;
  int b = i >> 5, sl = i & 31;
  int t = threadIdx.x;
  float* Wt   = (float*)smraw;                      // 64x64 = 16384 B
  float* actS = (float*)(smraw + 16384);            // 64x64 = 16384 B
  double (*rg)[4] = (double(*)[4])(smraw + 32768);  // 64 B
  float* bcst = (float*)(smraw + 32832);            // 2
  const double* gp = (const double*)(ws + OFF_GNP) + (size_t)b * CN * 2;
  double g1 = 0, g2 = 0;
  if (t < CN) { g1 = gp[2*t]; g2 = gp[2*t+1]; }
  for (int off = 32; off > 0; off >>= 1) { g1 += __shfl_down(g1, off); g2 += __shfl_down(g2, off); }
  {
    int w = t >> 6;
    if ((t & 63) == 0) { rg[0][w] = g1; rg[1][w] = g2; }
  }
  for (int q = t; q < 4096; q += NTH) {
    int o = q & 63, c = q >> 6;
    Wt[c * 64 + o] = proj_w[o * 64 + c];
  }
  __syncthreads();
  if (t == 0) {
    double S1 = rg[0][0]+rg[0][1]+rg[0][2]+rg[0][3];
    double S2 = rg[1][0]+rg[1][1]+rg[1][2]+rg[1][3];
    const double NN = 64.0 * 4096.0;
    double mud = S1 / NN;
    bcst[0] = (float)mud;
    bcst[1] = rsqrtf((float)(S2 / NN - mud * mud) + 1e-5f);
  }
  __syncthreads();
  float mu = bcst[0], rstd = bcst[1];
  float rsv = res_scale[0];
  const unsigned short* mx = (const unsigned short*)(ws + OFF_MIX) + (size_t)b * CN * LN;
  const float* xb = x + (size_t)b * CN * LN;
  float* ob = out + (size_t)b * CN * LN;
#pragma unroll 1
  for (int hh = 0; hh < 2; hh++) {
    int lbase = sl * 128 + hh * 64;
    for (int q = t; q < 2048; q += NTH) {
      int c = q >> 5, lp = (q & 31) * 2;
      unsigned v2 = *(const unsigned*)&mx[(size_t)c * LN + lbase + lp];
      float f0 = __uint_as_float(v2 << 16);
      float f1 = __uint_as_float(v2 & 0xFFFF0000u);
      float gA = (f0 - mu) * rstd * gn_g[c] + gn_b[c];
      float gB = (f1 - mu) * rstd * gn_g[c] + gn_b[c];
      actS[c * 64 + lp]     = 0.5f * gA * (1.f + erff(gA * 0.70710678118654752f));
      actS[c * 64 + lp + 1] = 0.5f * gB * (1.f + erff(gB * 0.70710678118654752f));
    }
    __syncthreads();
    int lq = t & 15, og = (t >> 4) * 4;
    float4 acc4[4];
#pragma unroll
    for (int oo = 0; oo < 4; oo++) acc4[oo] = make_float4(0.f, 0.f, 0.f, 0.f);
    for (int c = 0; c < 64; c++) {
      float4 av = *(const float4*)&actS[c * 64 + lq * 4];
      float4 wv = *(const float4*)&Wt[c * 64 + og];
      float wsc[4] = {wv.x, wv.y, wv.z, wv.w};
#pragma unroll
      for (int oo = 0; oo < 4; oo++) {
        acc4[oo].x = fmaf(wsc[oo], av.x, acc4[oo].x);
        acc4[oo].y = fmaf(wsc[oo], av.y, acc4[oo].y);
        acc4[oo].z = fmaf(wsc[oo], av.z, acc4[oo].z);
        acc4[oo].w = fmaf(wsc[oo], av.w, acc4[oo].w);
      }
    }
#pragma unroll
    for (int oo = 0; oo < 4; oo++) {
      int o = og + oo;
      float pb = proj_b[o];
      size_t base = (size_t)o * LN + lbase + lq * 4;
      float4 xv = *(const float4*)&xb[base];
      float4 rr2;
      rr2.x = xv.x + rsv * (acc4[oo].x + pb);
      rr2.y = xv.y + rsv * (acc4[oo].y + pb);
      rr2.z = xv.z + rsv * (acc4[oo].z + pb);
      rr2.w = xv.w + rsv * (acc4[oo].w + pb);
      *(float4*)&ob[base] = rr2;
    }
    __syncthreads();
  }
}

extern "C" void kernel_launch(void* const* d_in, const int* in_sizes, int n_in,
                              void* d_out, int out_size, void* d_ws, size_t ws_size,
                              hipStream_t stream) {
  const float* x        = (const float*)d_in[0];
  const float* dw7      = (const float*)d_in[1];
  const float* dw15     = (const float*)d_in[2];
  const float* dw31     = (const float*)d_in[3];
  const float* dw63     = (const float*)d_in[4];
  const float* bn_g     = (const float*)d_in[5];
  const float* bn_b     = (const float*)d_in[6];
  const float* bn_m     = (const float*)d_in[7];
  const float* bn_v     = (const float*)d_in[8];
  const float* comp_w1  = (const float*)d_in[9];
  const float* comp_b1  = (const float*)d_in[10];
  const float* comp_w2  = (const float*)d_in[11];
  const float* comp_b2  = (const float*)d_in[12];
  const float* pn_g     = (const float*)d_in[13];
  const float* pn_b     = (const float*)d_in[14];
  const float* pn_m     = (const float*)d_in[15];
  const float* pn_v     = (const float*)d_in[16];
  const float* pe_w1    = (const float*)d_in[17];
  const float* pe_b1    = (const float*)d_in[18];
  const float* pe_w2    = (const float*)d_in[19];
  const float* pe_b2    = (const float*)d_in[20];
  const float* pg_w     = (const float*)d_in[21];
  const float* pg_b     = (const float*)d_in[22];
  const float* temperature = (const float*)d_in[23];
  const float* gn_g     = (const float*)d_in[24];
  const float* gn_b     = (const float*)d_in[25];
  const float* proj_w   = (const float*)d_in[26];
  const float* proj_b   = (const float*)d_in[27];
  const float* res_scale= (const float*)d_in[28];
  float* ws = (float*)d_ws;
  float* out = (float*)d_out;

  hipLaunchKernelGGL(k1_spec, dim3(1024), dim3(NTH), 0, stream, x, ws);
  hipLaunchKernelGGL(k2_conv, dim3(1024), dim3(NTH), 0, stream,
                     x, dw7, dw15, dw31, dw63, bn_g, bn_b, bn_m, bn_v,
                     comp_w1, comp_b1, comp_w2, comp_b2,
                     pn_g, pn_b, pn_m, pn_v, pe_w1, pe_b1, pe_w2, pe_b2,
                     pg_w, pg_b, temperature, ws);
  hipLaunchKernelGGL(k3_final, dim3(1024), dim3(NTH), 0, stream,
                     x, proj_w, proj_b, gn_g, gn_b, res_scale, ws, out);
}

// Round 8
// 223.389 us; speedup vs baseline: 1.0319x; 1.0319x over previous
//
#include <hip/hip_runtime.h>
#include <math.h>

#define LN 4096
#define CN 64
#define NTH 256

// ws offsets (floats)
#define OFF_CHAN_SUM    0        // 2048
#define OFF_CHAN_JERK   2048     // 2048
#define OFF_CHAN_JRATE  4096     // 2048
#define OFF_CHAN_ZCR    6144     // 2048
#define OFF_SVMST_PART  8192     // 32 b * 32 chunks * 8 = 8192
#define OFF_SPEC_PART   16384    // 1024 * 3
#define OFF_GNP         19584    // 2048 double pairs (byte 78336 % 8 == 0)
#define OFF_SVMBUF      27776    // 32 * 4096
#define OFF_MIX         158848   // bf16 mixed: 32*64*4096 ushorts = 4194304 floats
// total ~4.35M floats = 17.4 MB (< ws)

#define FP(i) ((i) + ((i) >> 4))

__device__ __forceinline__ unsigned short f2bf(float f) {
  unsigned u = __float_as_uint(f);
  unsigned r = (u + 0x7FFFu + ((u >> 16) & 1u)) >> 16;
  return (unsigned short)r;
}

// radix-4 DIT butterfly in place; twiddles applied to b,c,d
__device__ __forceinline__ void bfly4(float2& a, float2& b, float2& c, float2& d,
                                      float w1r, float w1i, float w2r, float w2i,
                                      float w3r, float w3i) {
  float t1r = b.x*w1r - b.y*w1i, t1i = b.x*w1i + b.y*w1r;
  float t2r = c.x*w2r - c.y*w2i, t2i = c.x*w2i + c.y*w2r;
  float t3r = d.x*w3r - d.y*w3i, t3i = d.x*w3i + d.y*w3r;
  float ar = a.x + t2r, ai = a.y + t2i;
  float br = a.x - t2r, bi = a.y - t2i;
  float cr = t1r + t3r, ci = t1i + t3i;
  float dr = t1r - t3r, di = t1i - t3i;
  a = make_float2(ar + cr, ai + ci);
  b = make_float2(br + di, bi - dr);
  c = make_float2(ar - cr, ai - ci);
  d = make_float2(br - di, bi + dr);
}

__device__ __forceinline__ float4 ldmask(const float* __restrict__ row, int idx) {
  int idxc = idx < 0 ? 0 : (idx > LN - 4 ? LN - 4 : idx);
  float4 v = *(const float4*)(row + idxc);
  float m = (idx == idxc) ? 1.f : 0.f;
  v.x *= m; v.y *= m; v.z *= m; v.w *= m;
  return v;
}

#define F16(wv,a0,a1,a2,a3,a4,a5,a6,a7,a8,a9,aA,aB,aC,aD,aE,aF) \
  acc[0]=fmaf(wv,a0,acc[0]);  acc[1]=fmaf(wv,a1,acc[1]);  acc[2]=fmaf(wv,a2,acc[2]);  acc[3]=fmaf(wv,a3,acc[3]);  \
  acc[4]=fmaf(wv,a4,acc[4]);  acc[5]=fmaf(wv,a5,acc[5]);  acc[6]=fmaf(wv,a6,acc[6]);  acc[7]=fmaf(wv,a7,acc[7]);  \
  acc[8]=fmaf(wv,a8,acc[8]);  acc[9]=fmaf(wv,a9,acc[9]);  acc[10]=fmaf(wv,aA,acc[10]); acc[11]=fmaf(wv,aB,acc[11]); \
  acc[12]=fmaf(wv,aC,acc[12]); acc[13]=fmaf(wv,aD,acc[13]); acc[14]=fmaf(wv,aE,acc[14]); acc[15]=fmaf(wv,aF,acc[15]);

// ================= k1: svm slice + FFT (2 real ch packed) + fused row scans =================
__global__ __launch_bounds__(NTH) void k1_spec(const float* __restrict__ x, float* __restrict__ ws) {
  __shared__ __align__(16) char smraw[35072];
  int i = blockIdx.x;
  int b = i >> 5, sl = i & 31;   // 32 batches x 32 slots
  int t = threadIdx.x;

  // ---- P1a: svm slice (128 l per block, all 64 channels) ----
  {
    float* tmp = (float*)smraw;                       // 128 floats
    float (*sred)[8] = (float(*)[8])(smraw + 512);    // [2][8]
    int lt = t & 127, ch = t >> 7;
    int l = sl * 128 + lt;
    const float* xb = x + (size_t)b * CN * LN + l;
    float acc = 0.f;
#pragma unroll
    for (int cc = 0; cc < 32; cc++) {
      float v = xb[(size_t)(ch * 32 + cc) * LN];
      acc = fmaf(v, v, acc);
    }
    if (ch == 1) tmp[lt] = acc;
    __syncthreads();
    if (ch == 0) {
      acc += tmp[lt];
      float svm = sqrtf(acc);
      ws[OFF_SVMBUF + (size_t)b * LN + l] = svm;
      const int third = LN / 3;     // 1365
      float vS = svm, vS2 = svm * svm;
      float vS2H  = (l >= LN/2) ? svm : 0.f;
      float vS2H2 = (l >= LN/2) ? svm * svm : 0.f;
      float vPRE  = (l < third) ? svm : 0.f;
      float vPOST = (l >= 2*third) ? svm : 0.f;
      float vMX = svm;
      float vMID = (l >= third && l < 2*third) ? svm : 0.f;
      for (int off = 32; off > 0; off >>= 1) {
        vS += __shfl_down(vS, off); vS2 += __shfl_down(vS2, off);
        vS2H += __shfl_down(vS2H, off); vS2H2 += __shfl_down(vS2H2, off);
        vPRE += __shfl_down(vPRE, off); vPOST += __shfl_down(vPOST, off);
        vMX = fmaxf(vMX, __shfl_down(vMX, off));
        vMID = fmaxf(vMID, __shfl_down(vMID, off));
      }
      if ((t & 63) == 0) {
        int w = t >> 6;
        sred[w][0]=vS; sred[w][1]=vS2; sred[w][2]=vMX; sred[w][3]=vS2H;
        sred[w][4]=vS2H2; sred[w][5]=vPRE; sred[w][6]=vMID; sred[w][7]=vPOST;
      }
    }
    __syncthreads();
    if (t == 0) {
      float* sp = ws + OFF_SVMST_PART + (size_t)(b * 32 + sl) * 8;
      sp[0]=sred[0][0]+sred[1][0];
      sp[1]=sred[0][1]+sred[1][1];
      sp[2]=fmaxf(sred[0][2],sred[1][2]);
      sp[3]=sred[0][3]+sred[1][3];
      sp[4]=sred[0][4]+sred[1][4];
      sp[5]=sred[0][5]+sred[1][5];
      sp[6]=fmaxf(sred[0][6],sred[1][6]);
      sp[7]=sred[0][7]+sred[1][7];
    }
    __syncthreads();   // before FFT overwrites smraw
  }

  // ---- P1b: FFT + fused row scans ----
  {
    const float* r0 = x + ((size_t)b * CN + 2 * sl) * LN;
    const float* r1 = r0 + LN;
    float2* z = (float2*)smraw;                        // FP(4096) float2 < 34816 B
    float (*sred8)[8] = (float(*)[8])(smraw + 34816);  // [4][8] scan partials
    float s0 = 0.f, jm0 = 0.f, jr0 = 0.f; int zc0 = 0;
    float s1v = 0.f, jm1 = 0.f, jr1 = 0.f; int zc1 = 0;
#pragma unroll
    for (int k = 0; k < 4; k++) {
      int n4 = (k * 256 + t) * 4;
      float4 a = *(const float4*)(r0 + n4);
      float4 c = *(const float4*)(r1 + n4);
      float a4 = __shfl_down(a.x, 1), a5 = __shfl_down(a.y, 1);
      float c4 = __shfl_down(c.x, 1), c5 = __shfl_down(c.y, 1);
      if ((t & 63) == 63) {
        a4 = (n4 + 4 < LN) ? r0[n4 + 4] : 0.f;
        a5 = (n4 + 5 < LN) ? r0[n4 + 5] : 0.f;
        c4 = (n4 + 4 < LN) ? r1[n4 + 4] : 0.f;
        c5 = (n4 + 5 < LN) ? r1[n4 + 5] : 0.f;
      }
      bool nl = (n4 + 4 < LN);
      s0 += a.x + a.y + a.z + a.w;
      jm0 = fmaxf(jm0, fmaxf(fmaxf(fabsf(a.y-a.x), fabsf(a.z-a.y)), fabsf(a.w-a.z)));
      zc0 += (a.x*a.y < 0.f) + (a.y*a.z < 0.f) + (a.z*a.w < 0.f);
      jr0 = fmaxf(jr0, fmaxf(fabsf(a.z - 2.f*a.y + a.x), fabsf(a.w - 2.f*a.z + a.y)));
      if (nl) {
        jm0 = fmaxf(jm0, fabsf(a4 - a.w));
        zc0 += (a.w * a4 < 0.f);
        jr0 = fmaxf(jr0, fmaxf(fabsf(a4 - 2.f*a.w + a.z), fabsf(a5 - 2.f*a4 + a.w)));
      }
      s1v += c.x + c.y + c.z + c.w;
      jm1 = fmaxf(jm1, fmaxf(fmaxf(fabsf(c.y-c.x), fabsf(c.z-c.y)), fabsf(c.w-c.z)));
      zc1 += (c.x*c.y < 0.f) + (c.y*c.z < 0.f) + (c.z*c.w < 0.f);
      jr1 = fmaxf(jr1, fmaxf(fabsf(c.z - 2.f*c.y + c.x), fabsf(c.w - 2.f*c.z + c.y)));
      if (nl) {
        jm1 = fmaxf(jm1, fabsf(c4 - c.w));
        zc1 += (c.w * c4 < 0.f);
        jr1 = fmaxf(jr1, fmaxf(fabsf(c4 - 2.f*c.w + c.z), fabsf(c5 - 2.f*c4 + c.w)));
      }
      float ar[4] = {a.x, a.y, a.z, a.w}, crr[4] = {c.x, c.y, c.z, c.w};
#pragma unroll
      for (int q = 0; q < 4; q++) {
        unsigned n = (unsigned)(n4 + q);
        unsigned br = __brev(n) >> 20;
        unsigned dr = ((br & 0x555u) << 1) | ((br & 0xAAAu) >> 1);
        z[FP(dr)] = make_float2(ar[q], crr[q]);
      }
    }
    for (int off = 32; off > 0; off >>= 1) {
      s0 += __shfl_down(s0, off); jm0 = fmaxf(jm0, __shfl_down(jm0, off));
      jr0 = fmaxf(jr0, __shfl_down(jr0, off)); zc0 += __shfl_down(zc0, off);
      s1v += __shfl_down(s1v, off); jm1 = fmaxf(jm1, __shfl_down(jm1, off));
      jr1 = fmaxf(jr1, __shfl_down(jr1, off)); zc1 += __shfl_down(zc1, off);
    }
    if ((t & 63) == 0) {
      int w = t >> 6;
      sred8[w][0]=s0; sred8[w][1]=jm0; sred8[w][2]=jr0; sred8[w][3]=(float)zc0;
      sred8[w][4]=s1v; sred8[w][5]=jm1; sred8[w][6]=jr1; sred8[w][7]=(float)zc1;
    }
    __syncthreads();
    if (t == 0) {
      int bc0 = b * CN + 2 * sl;
      float S0=0,J0=0,JR0=0,Z0=0,S1=0,J1=0,JR1=0,Z1=0;
      for (int w = 0; w < 4; w++) {
        S0 += sred8[w][0]; J0 = fmaxf(J0, sred8[w][1]); JR0 = fmaxf(JR0, sred8[w][2]); Z0 += sred8[w][3];
        S1 += sred8[w][4]; J1 = fmaxf(J1, sred8[w][5]); JR1 = fmaxf(JR1, sred8[w][6]); Z1 += sred8[w][7];
      }
      ws[OFF_CHAN_SUM + bc0]       = S0;           ws[OFF_CHAN_SUM + bc0 + 1]   = S1;
      ws[OFF_CHAN_JERK + bc0]      = J0 * 50.f;    ws[OFF_CHAN_JERK + bc0 + 1]  = J1 * 50.f;
      ws[OFF_CHAN_JRATE + bc0]     = JR0 * 2500.f; ws[OFF_CHAN_JRATE + bc0 + 1] = JR1 * 2500.f;
      ws[OFF_CHAN_ZCR + bc0]       = Z0;           ws[OFF_CHAN_ZCR + bc0 + 1]   = Z1;
    }
    const float c8r[4] = { 1.f, 0.92387953251f, 0.70710678119f, 0.38268343236f };
    const float c8i[4] = { 0.f, -0.38268343236f, -0.70710678119f, -0.92387953251f };
#pragma unroll
    for (int p = 0; p < 3; p++) {
      const int H = (p == 0) ? 1 : (p == 1) ? 16 : 256;
      int rr = t & (H - 1);
      int B = ((t / H) * 16 * H) + rr;
      float2 E[16];
#pragma unroll
      for (int q = 0; q < 16; q++) E[q] = z[FP(B + q * H)];
      float su, cu;
      sincospif((float)rr / (8.0f * (float)H), &su, &cu);
      float ur = cu, ui = -su;
      float u2r = ur*ur - ui*ui, u2i = 2.f*ur*ui;
      float w1r = u2r*u2r - u2i*u2i, w1i = 2.f*u2r*u2i;      // u^4
      float w2r = w1r*w1r - w1i*w1i, w2i = 2.f*w1r*w1i;       // u^8
      float w3r = w2r*w1r - w2i*w1i, w3i = w2r*w1i + w2i*w1r; // u^12
#pragma unroll
      for (int m = 0; m < 4; m++)
        bfly4(E[4*m], E[4*m+1], E[4*m+2], E[4*m+3], w1r, w1i, w2r, w2i, w3r, w3i);
#pragma unroll
      for (int m = 0; m < 4; m++) {
        float W1r = ur*c8r[m] - ui*c8i[m];
        float W1i = ur*c8i[m] + ui*c8r[m];
        float W2r = W1r*W1r - W1i*W1i, W2i = 2.f*W1r*W1i;
        float W3r = W2r*W1r - W2i*W1i, W3i = W2r*W1i + W2i*W1r;
        bfly4(E[m], E[m+4], E[m+8], E[m+12], W1r, W1i, W2r, W2i, W3r, W3i);
      }
#pragma unroll
      for (int q = 0; q < 16; q++) z[FP(B + q * H)] = E[q];
      __syncthreads();
    }
    float tot = 0.f, cen = 0.f, hi = 0.f;
    for (int k = t; k <= LN / 2; k += NTH) {
      float p;
      if (k == 0 || k == LN / 2) {
        float2 v = z[FP(k)];
        p = v.x * v.x + v.y * v.y;
      } else {
        float2 zk = z[FP(k)], zn = z[FP(LN - k)];
        float a1 = zk.x + zn.x, a2 = zk.y - zn.y, a3 = zk.y + zn.y, a4v = zk.x - zn.x;
        p = 0.25f * (a1*a1 + a2*a2 + a3*a3 + a4v*a4v);
      }
      p *= (1.0f / LN);
      tot += p;
      cen += p * ((float)k * (1.0f / (LN / 2)));
      if (k >= 820) hi += p;
    }
    for (int off = 32; off > 0; off >>= 1) {
      tot += __shfl_down(tot, off);
      cen += __shfl_down(cen, off);
      hi  += __shfl_down(hi, off);
    }
    float (*redS)[4] = (float(*)[4])(smraw + 34816);
    if ((t & 63) == 0) { int w = t >> 6; redS[0][w] = tot; redS[1][w] = cen; redS[2][w] = hi; }
    __syncthreads();
    if (t == 0) {
      float* sp = ws + OFF_SPEC_PART + (size_t)(b * 32 + sl) * 3;
      sp[0] = redS[0][0]+redS[0][1]+redS[0][2]+redS[0][3];
      sp[1] = redS[1][0]+redS[1][1]+redS[1][2]+redS[1][3];
      sp[2] = redS[2][0]+redS[2][1]+redS[2][2]+redS[2][3];
    }
  }
}

// ================= k2: gate (redundant per block) + eff weights + conv (1 row/block, 2048 blocks) =================
__global__ __launch_bounds__(NTH) void k2_conv(
    const float* __restrict__ x,
    const float* __restrict__ dw7, const float* __restrict__ dw15,
    const float* __restrict__ dw31, const float* __restrict__ dw63,
    const float* __restrict__ bn_g, const float* __restrict__ bn_b,
    const float* __restrict__ bn_m, const float* __restrict__ bn_v,
    const float* __restrict__ comp_w1, const float* __restrict__ comp_b1,
    const float* __restrict__ comp_w2, const float* __restrict__ comp_b2,
    const float* __restrict__ pn_g, const float* __restrict__ pn_b,
    const float* __restrict__ pn_m, const float* __restrict__ pn_v,
    const float* __restrict__ pe_w1, const float* __restrict__ pe_b1,
    const float* __restrict__ pe_w2, const float* __restrict__ pe_b2,
    const float* __restrict__ pg_w, const float* __restrict__ pg_b,
    const float* __restrict__ temperature,
    float* __restrict__ ws)
{
  int i = blockIdx.x;
  int b = i >> 6, c = i & 63;      // 32 batches x 64 channels
  int t = threadIdx.x;
  __shared__ float sp8[32][8];
  __shared__ float sp3[32][3];
  __shared__ float stv[10];
  __shared__ float bc2[2];
  __shared__ float xm[64], h[64], pf[12], pe1v[32], pe2v[32], lgts[4], swts[4];
  __shared__ int ri[3][4], cnts[3];
  __shared__ float cwt[64];
  __shared__ float cbias;
  __shared__ double rda[2][4];

  // ---- gate (round-2 structure, verbatim; redundant per block) ----
  if (t < 32) {
    const float* p = ws + OFF_SVMST_PART + (size_t)(b * 32 + t) * 8;
#pragma unroll
    for (int q = 0; q < 8; q++) sp8[t][q] = p[q];
  }
  if (t >= 32 && t < 64) {
    int q = t - 32;
    const float* p = ws + OFF_SPEC_PART + (size_t)(b * 32 + q) * 3;
    sp3[q][0] = p[0]; sp3[q][1] = p[1]; sp3[q][2] = p[2];
  }
  __syncthreads();
  if (t == 0) {
    float S=0,S2=0,MX=-1e30f,S2H=0,S2H2=0,PRE=0,MID=-1e30f,POST=0;
    for (int q = 0; q < 32; q++) {
      S += sp8[q][0]; S2 += sp8[q][1]; MX = fmaxf(MX, sp8[q][2]);
      S2H += sp8[q][3]; S2H2 += sp8[q][4]; PRE += sp8[q][5];
      MID = fmaxf(MID, sp8[q][6]); POST += sp8[q][7];
    }
    float tt=0,ce=0,hh=0;
    for (int q = 0; q < 32; q++) { tt += sp3[q][0]; ce += sp3[q][1]; hh += sp3[q][2]; }
    stv[0]=S; stv[1]=S2; stv[2]=MX; stv[3]=S2H; stv[4]=S2H2;
    stv[5]=PRE; stv[6]=MID; stv[7]=POST; stv[8]=ce/(tt+1e-6f); stv[9]=hh/(tt+1e-6f);
    float mean = S * (1.f / LN);
    float var = (S2 - S * S * (1.f / LN)) * (1.f / (LN - 1));
    var = fmaxf(var, 0.f);
    bc2[0] = mean;
    bc2[1] = sqrtf(var) + 1e-6f;
  }
  __syncthreads();
  float mean = bc2[0], stde = bc2[1];
  float thr2 = mean + 2.f * stde, thr3 = mean + 3.f * stde, thrf = mean - stde;
  const float* svm = ws + OFF_SVMBUF + (size_t)b * LN;
  int cc2 = 0, cc3 = 0, ccf = 0;
  for (int l = t; l < LN; l += NTH) {
    float v = svm[l];
    cc2 += (v > thr2); cc3 += (v > thr3); ccf += (v < thrf);
  }
  for (int off = 32; off > 0; off >>= 1) {
    cc2 += __shfl_down(cc2, off); cc3 += __shfl_down(cc3, off); ccf += __shfl_down(ccf, off);
  }
  {
    int w = t >> 6;
    if ((t & 63) == 0) { ri[0][w] = cc2; ri[1][w] = cc3; ri[2][w] = ccf; }
  }
  float j = 0.f, jr = 0.f, zz = 0.f;
  if (t < 64) {
    xm[t] = ws[OFF_CHAN_SUM + b * 64 + t] * (1.0f / LN);
    j  = ws[OFF_CHAN_JERK + b * 64 + t];
    jr = ws[OFF_CHAN_JRATE + b * 64 + t];
    zz = ws[OFF_CHAN_ZCR + b * 64 + t];
    for (int off = 32; off > 0; off >>= 1) {
      j += __shfl_down(j, off); jr += __shfl_down(jr, off); zz += __shfl_down(zz, off);
    }
  }
  __syncthreads();
  if (t == 0) {
    cnts[0] = ri[0][0]+ri[0][1]+ri[0][2]+ri[0][3];
    cnts[1] = ri[1][0]+ri[1][1]+ri[1][2]+ri[1][3];
    cnts[2] = ri[2][0]+ri[2][1]+ri[2][2]+ri[2][3];
    const int third = LN / 3;
    float S2H = stv[3], S2H2 = stv[4];
    float n2 = (float)(LN / 2);
    float var2 = (S2H2 - S2H * S2H / n2) / (n2 - 1.f);
    var2 = fmaxf(var2, 0.f);
    float post_still = tanhf(1.f / (sqrtf(var2) + 1e-6f));
    float pre_mean = stv[5] / (float)third;
    float post_mean = stv[7] / (float)(LN - 2 * third);
    float pk = stv[6];
    float fp2 = fmaxf(pk - pre_mean, 0.f) + fmaxf(pk - post_mean, 0.f);
    fp2 = fp2 / (fabsf(pk) + 1e-6f);
    pf[0] = stv[2];
    pf[1] = mean;
    pf[2] = j * (1.f / 64);
    pf[3] = jr * (1.f / 64);
    pf[4] = (zz * (1.f / 64)) * (1.f / LN);
    pf[5] = (float)cnts[0] / LN;
    pf[6] = (float)cnts[1] / LN;
    pf[7] = post_still;
    pf[8] = (float)cnts[2] / LN;
    pf[9] = stv[8];
    pf[10] = stv[9];
    pf[11] = fp2;
  }
  __syncthreads();
  if (t < 12) pf[t] = (pf[t] - pn_m[t]) * rsqrtf(pn_v[t] + 1e-5f) * pn_g[t] + pn_b[t];
  __syncthreads();
  if (t < 64) {
    float hv = comp_b1[t];
    for (int q = 0; q < 64; q++) hv = fmaf(xm[q], comp_w1[q * 64 + t], hv);
    h[t] = fmaxf(hv, 0.f);
  }
  if (t < 32) {
    float v = pe_b1[t];
    for (int q = 0; q < 12; q++) v = fmaf(pf[q], pe_w1[q * 32 + t], v);
    pe1v[t] = fmaxf(v, 0.f);
  }
  __syncthreads();
  if (t < 32) {
    float v = pe_b2[t];
    for (int q = 0; q < 32; q++) v = fmaf(pe1v[q], pe_w2[q * 32 + t], v);
    pe2v[t] = fmaxf(v, 0.f);
  }
  __syncthreads();
  if (t < 4) {
    float v = comp_b2[t];
    for (int q = 0; q < 64; q++) v = fmaf(h[q], comp_w2[q * 4 + t], v);
    float g = pg_b[t];
    for (int q = 0; q < 32; q++) g = fmaf(pe2v[q], pg_w[q * 4 + t], g);
    g = 1.f / (1.f + expf(-g));
    float temp = fmaxf(temperature[0], 0.1f);
    lgts[t] = v * g / temp;
  }
  __syncthreads();
  if (t < 4) {
    float m = fmaxf(fmaxf(lgts[0], lgts[1]), fmaxf(lgts[2], lgts[3]));
    float den = expf(lgts[0]-m) + expf(lgts[1]-m) + expf(lgts[2]-m) + expf(lgts[3]-m);
    swts[t] = expf(lgts[t] - m) / den;
  }
  __syncthreads();

  // ---- eff weights for this block's single channel ----
  if (t < 64) {
    int tau = t;
    float w0 = swts[0], w1 = swts[1], w2 = swts[2], w3 = swts[3];
    float sc0 = bn_g[0*64+c] * rsqrtf(bn_v[0*64+c] + 1e-5f);
    float sc1 = bn_g[1*64+c] * rsqrtf(bn_v[1*64+c] + 1e-5f);
    float sc2 = bn_g[2*64+c] * rsqrtf(bn_v[2*64+c] + 1e-5f);
    float sc3 = bn_g[3*64+c] * rsqrtf(bn_v[3*64+c] + 1e-5f);
    float a0 = w0*sc0, a1 = w1*sc1, a2 = w2*sc2, a3 = w3*sc3;
    if (tau == 0) {
      float o0 = bn_b[0*64+c] - bn_m[0*64+c] * sc0;
      float o1 = bn_b[1*64+c] - bn_m[1*64+c] * sc1;
      float o2 = bn_b[2*64+c] - bn_m[2*64+c] * sc2;
      float o3 = bn_b[3*64+c] - bn_m[3*64+c] * sc3;
      cbias = w0*o0 + w1*o1 + w2*o2 + w3*o3;
    }
    float v = 0.f;
    if (tau < 63) {
      v = a3 * dw63[c * 63 + tau];
      int i7 = tau - 28;  if (i7 >= 0 && i7 < 7)    v = fmaf(a0, dw7[c * 7 + i7], v);
      int i15 = tau - 24; if (i15 >= 0 && i15 < 15) v = fmaf(a1, dw15[c * 15 + i15], v);
      int i31 = tau - 16; if (i31 >= 0 && i31 < 31) v = fmaf(a2, dw31[c * 31 + i31], v);
    }
    cwt[tau] = v;
  }
  __syncthreads();

  // ---- conv: single row, 5-register sliding window; bf16 output to ws ----
  {
    const float* row = x + ((size_t)b * CN + c) * LN;
    float bias = cbias;
    int l0 = t * 16, g0 = l0 - 32;
    float4 R0 = ldmask(row, g0);
    float4 R1 = ldmask(row, g0 + 4);
    float4 R2 = ldmask(row, g0 + 8);
    float4 R3 = ldmask(row, g0 + 12);
    float4 R4 = ldmask(row, g0 + 16);
    float acc[16];
#pragma unroll
    for (int q = 0; q < 16; q++) acc[q] = bias;
#pragma unroll
    for (int g = 0; g < 16; g++) {
      float w0 = cwt[4*g], w1 = cwt[4*g+1], w2 = cwt[4*g+2], w3 = cwt[4*g+3];
      F16(w0, R0.y,R0.z,R0.w,R1.x,R1.y,R1.z,R1.w,R2.x,R2.y,R2.z,R2.w,R3.x,R3.y,R3.z,R3.w,R4.x)
      F16(w1, R0.z,R0.w,R1.x,R1.y,R1.z,R1.w,R2.x,R2.y,R2.z,R2.w,R3.x,R3.y,R3.z,R3.w,R4.x,R4.y)
      F16(w2, R0.w,R1.x,R1.y,R1.z,R1.w,R2.x,R2.y,R2.z,R2.w,R3.x,R3.y,R3.z,R3.w,R4.x,R4.y,R4.z)
      F16(w3, R1.x,R1.y,R1.z,R1.w,R2.x,R2.y,R2.z,R2.w,R3.x,R3.y,R3.z,R3.w,R4.x,R4.y,R4.z,R4.w)
      if (g < 15) {
        R0 = R1; R1 = R2; R2 = R3; R3 = R4;
        R4 = ldmask(row, g0 + 4 * (g + 5));
      }
    }
    double ls = 0, ls2 = 0;
#pragma unroll
    for (int q = 0; q < 16; q++) { float v = acc[q]; ls += v; ls2 += (double)v * (double)v; }
    for (int off = 32; off > 0; off >>= 1) {
      ls += __shfl_down(ls, off);
      ls2 += __shfl_down(ls2, off);
    }
    int w = t >> 6;
    if ((t & 63) == 0) { rda[0][w] = ls; rda[1][w] = ls2; }
    // bf16 pack: 16 values -> 8 u32 -> 2 uint4 stores (32 B/thread, contiguous)
    unsigned short* mdst = (unsigned short*)(ws + OFF_MIX) + ((size_t)(b * CN + c)) * LN + l0;
    unsigned pk[8];
#pragma unroll
    for (int q = 0; q < 8; q++)
      pk[q] = (unsigned)f2bf(acc[2*q]) | ((unsigned)f2bf(acc[2*q+1]) << 16);
    uint4 v0 = make_uint4(pk[0], pk[1], pk[2], pk[3]);
    uint4 v1 = make_uint4(pk[4], pk[5], pk[6], pk[7]);
    *(uint4*)(mdst) = v0;
    *(uint4*)(mdst + 8) = v1;
    __syncthreads();
    if (t == 0) {
      double* gp = (double*)(ws + OFF_GNP);
      gp[2 * (b * CN + c) + 0] = rda[0][0]+rda[0][1]+rda[0][2]+rda[0][3];
      gp[2 * (b * CN + c) + 1] = rda[1][0]+rda[1][1]+rda[1][2]+rda[1][3];
    }
  }
}

// ================= k3: GN + GELU + proj + residual (2 x 64-l passes, bf16 mixed in) =================
__global__ __launch_bounds__(NTH) void k3_final(const float* __restrict__ x,
    const float* __restrict__ proj_w, const float* __restrict__ proj_b,
    const float* __restrict__ gn_g, const float* __restrict__ gn_b,
    const float* __restrict__ res_scale,
    const float* __restrict__ ws, float* out) {
  __shared__ __align__(16) char smraw[32840];
  int i = blockIdx.x;
  int b = i >> 5, sl = i & 31;
  int t = threadIdx.x;
  float* Wt   = (float*)smraw;                      // 64x64 = 16384 B
  float* actS = (float*)(smraw + 16384);            // 64x64 = 16384 B
  double (*rg)[4] = (double(*)[4])(smraw + 32768);  // 64 B
  float* bcst = (float*)(smraw + 32832);            // 2
  const double* gp = (const double*)(ws + OFF_GNP) + (size_t)b * CN * 2;
  double g1 = 0, g2 = 0;
  if (t < CN) { g1 = gp[2*t]; g2 = gp[2*t+1]; }
  for (int off = 32; off > 0; off >>= 1) { g1 += __shfl_down(g1, off); g2 += __shfl_down(g2, off); }
  {
    int w = t >> 6;
    if ((t & 63) == 0) { rg[0][w] = g1; rg[1][w] = g2; }
  }
  for (int q = t; q < 4096; q += NTH) {
    int o = q & 63, c = q >> 6;
    Wt[c * 64 + o] = proj_w[o * 64 + c];
  }
  __syncthreads();
  if (t == 0) {
    double S1 = rg[0][0]+rg[0][1]+rg[0][2]+rg[0][3];
    double S2 = rg[1][0]+rg[1][1]+rg[1][2]+rg[1][3];
    const double NN = 64.0 * 4096.0;
    double mud = S1 / NN;
    bcst[0] = (float)mud;
    bcst[1] = rsqrtf((float)(S2 / NN - mud * mud) + 1e-5f);
  }
  __syncthreads();
  float mu = bcst[0], rstd = bcst[1];
  float rsv = res_scale[0];
  const unsigned short* mx = (const unsigned short*)(ws + OFF_MIX) + (size_t)b * CN * LN;
  const float* xb = x + (size_t)b * CN * LN;
  float* ob = out + (size_t)b * CN * LN;
#pragma unroll 1
  for (int hh = 0; hh < 2; hh++) {
    int lbase = sl * 128 + hh * 64;
    for (int q = t; q < 2048; q += NTH) {
      int c = q >> 5, lp = (q & 31) * 2;
      unsigned v2 = *(const unsigned*)&mx[(size_t)c * LN + lbase + lp];
      float f0 = __uint_as_float(v2 << 16);
      float f1 = __uint_as_float(v2 & 0xFFFF0000u);
      float gA = (f0 - mu) * rstd * gn_g[c] + gn_b[c];
      float gB = (f1 - mu) * rstd * gn_g[c] + gn_b[c];
      actS[c * 64 + lp]     = 0.5f * gA * (1.f + erff(gA * 0.70710678118654752f));
      actS[c * 64 + lp + 1] = 0.5f * gB * (1.f + erff(gB * 0.70710678118654752f));
    }
    __syncthreads();
    int lq = t & 15, og = (t >> 4) * 4;
    float4 acc4[4];
#pragma unroll
    for (int oo = 0; oo < 4; oo++) acc4[oo] = make_float4(0.f, 0.f, 0.f, 0.f);
    for (int c = 0; c < 64; c++) {
      float4 av = *(const float4*)&actS[c * 64 + lq * 4];
      float4 wv = *(const float4*)&Wt[c * 64 + og];
      float wsc[4] = {wv.x, wv.y, wv.z, wv.w};
#pragma unroll
      for (int oo = 0; oo < 4; oo++) {
        acc4[oo].x = fmaf(wsc[oo], av.x, acc4[oo].x);
        acc4[oo].y = fmaf(wsc[oo], av.y, acc4[oo].y);
        acc4[oo].z = fmaf(wsc[oo], av.z, acc4[oo].z);
        acc4[oo].w = fmaf(wsc[oo], av.w, acc4[oo].w);
      }
    }
#pragma unroll
    for (int oo = 0; oo < 4; oo++) {
      int o = og + oo;
      float pb = proj_b[o];
      size_t base = (size_t)o * LN + lbase + lq * 4;
      float4 xv = *(const float4*)&xb[base];
      float4 rr2;
      rr2.x = xv.x + rsv * (acc4[oo].x + pb);
      rr2.y = xv.y + rsv * (acc4[oo].y + pb);
      rr2.z = xv.z + rsv * (acc4[oo].z + pb);
      rr2.w = xv.w + rsv * (acc4[oo].w + pb);
      *(float4*)&ob[base] = rr2;
    }
    __syncthreads();
  }
}

extern "C" void kernel_launch(void* const* d_in, const int* in_sizes, int n_in,
                              void* d_out, int out_size, void* d_ws, size_t ws_size,
                              hipStream_t stream) {
  const float* x        = (const float*)d_in[0];
  const float* dw7      = (const float*)d_in[1];
  const float* dw15     = (const float*)d_in[2];
  const float* dw31     = (const float*)d_in[3];
  const float* dw63     = (const float*)d_in[4];
  const float* bn_g     = (const float*)d_in[5];
  const float* bn_b     = (const float*)d_in[6];
  const float* bn_m     = (const float*)d_in[7];
  const float* bn_v     = (const float*)d_in[8];
  const float* comp_w1  = (const float*)d_in[9];
  const float* comp_b1  = (const float*)d_in[10];
  const float* comp_w2  = (const float*)d_in[11];
  const float* comp_b2  = (const float*)d_in[12];
  const float* pn_g     = (const float*)d_in[13];
  const float* pn_b     = (const float*)d_in[14];
  const float* pn_m     = (const float*)d_in[15];
  const float* pn_v     = (const float*)d_in[16];
  const float* pe_w1    = (const float*)d_in[17];
  const float* pe_b1    = (const float*)d_in[18];
  const float* pe_w2    = (const float*)d_in[19];
  const float* pe_b2    = (const float*)d_in[20];
  const float* pg_w     = (const float*)d_in[21];
  const float* pg_b     = (const float*)d_in[22];
  const float* temperature = (const float*)d_in[23];
  const float* gn_g     = (const float*)d_in[24];
  const float* gn_b     = (const float*)d_in[25];
  const float* proj_w   = (const float*)d_in[26];
  const float* proj_b   = (const float*)d_in[27];
  const float* res_scale= (const float*)d_in[28];
  float* ws = (float*)d_ws;
  float* out = (float*)d_out;

  hipLaunchKernelGGL(k1_spec, dim3(1024), dim3(NTH), 0, stream, x, ws);
  hipLaunchKernelGGL(k2_conv, dim3(2048), dim3(NTH), 0, stream,
                     x, dw7, dw15, dw31, dw63, bn_g, bn_b, bn_m, bn_v,
                     comp_w1, comp_b1, comp_w2, comp_b2,
                     pn_g, pn_b, pn_m, pn_v, pe_w1, pe_b1, pe_w2, pe_b2,
                     pg_w, pg_b, temperature, ws);
  hipLaunchKernelGGL(k3_final, dim3(1024), dim3(NTH), 0, stream,
                     x, proj_w, proj_b, gn_g, gn_b, res_scale, ws, out);
}

// Round 10
// 220.223 us; speedup vs baseline: 1.0467x; 1.0144x over previous
//
#include <hip/hip_runtime.h>
#include <math.h>

#define LN 4096
#define CN 64
#define NTH 256

// ws offsets (floats)
#define OFF_CHAN_SUM    0        // 2048
#define OFF_CHAN_JERK   2048     // 2048
#define OFF_CHAN_JRATE  4096     // 2048
#define OFF_CHAN_ZCR    6144     // 2048
#define OFF_SVMST_PART  8192     // 32 b * 32 chunks * 8 = 8192
#define OFF_SPEC_PART   16384    // 1024 * 3
#define OFF_GNP         19584    // 2048 double pairs (byte 78336 % 8 == 0)
#define OFF_SVMBUF      27776    // 32 * 4096
#define OFF_MIX         158848   // bf16 mixed: 32*64*4096 ushorts = 4194304 floats
// total ~4.35M floats = 17.4 MB (< ws)

#define FP(i) ((i) + ((i) >> 4))

__device__ __forceinline__ unsigned short f2bf(float f) {
  unsigned u = __float_as_uint(f);
  unsigned r = (u + 0x7FFFu + ((u >> 16) & 1u)) >> 16;
  return (unsigned short)r;
}

// radix-4 DIT butterfly in place; twiddles applied to b,c,d
__device__ __forceinline__ void bfly4(float2& a, float2& b, float2& c, float2& d,
                                      float w1r, float w1i, float w2r, float w2i,
                                      float w3r, float w3i) {
  float t1r = b.x*w1r - b.y*w1i, t1i = b.x*w1i + b.y*w1r;
  float t2r = c.x*w2r - c.y*w2i, t2i = c.x*w2i + c.y*w2r;
  float t3r = d.x*w3r - d.y*w3i, t3i = d.x*w3i + d.y*w3r;
  float ar = a.x + t2r, ai = a.y + t2i;
  float br = a.x - t2r, bi = a.y - t2i;
  float cr = t1r + t3r, ci = t1i + t3i;
  float dr = t1r - t3r, di = t1i - t3i;
  a = make_float2(ar + cr, ai + ci);
  b = make_float2(br + di, bi - dr);
  c = make_float2(ar - cr, ai - ci);
  d = make_float2(br - di, bi + dr);
}

__device__ __forceinline__ float4 ldmask(const float* __restrict__ row, int idx) {
  int idxc = idx < 0 ? 0 : (idx > LN - 4 ? LN - 4 : idx);
  float4 v = *(const float4*)(row + idxc);
  float m = (idx == idxc) ? 1.f : 0.f;
  v.x *= m; v.y *= m; v.z *= m; v.w *= m;
  return v;
}

#define F16(wv,a0,a1,a2,a3,a4,a5,a6,a7,a8,a9,aA,aB,aC,aD,aE,aF) \
  acc[0]=fmaf(wv,a0,acc[0]);  acc[1]=fmaf(wv,a1,acc[1]);  acc[2]=fmaf(wv,a2,acc[2]);  acc[3]=fmaf(wv,a3,acc[3]);  \
  acc[4]=fmaf(wv,a4,acc[4]);  acc[5]=fmaf(wv,a5,acc[5]);  acc[6]=fmaf(wv,a6,acc[6]);  acc[7]=fmaf(wv,a7,acc[7]);  \
  acc[8]=fmaf(wv,a8,acc[8]);  acc[9]=fmaf(wv,a9,acc[9]);  acc[10]=fmaf(wv,aA,acc[10]); acc[11]=fmaf(wv,aB,acc[11]); \
  acc[12]=fmaf(wv,aC,acc[12]); acc[13]=fmaf(wv,aD,acc[13]); acc[14]=fmaf(wv,aE,acc[14]); acc[15]=fmaf(wv,aF,acc[15]);

// ================= k1: svm slice + FFT (2 real ch packed) + fused row scans =================
__global__ __launch_bounds__(NTH) void k1_spec(const float* __restrict__ x, float* __restrict__ ws) {
  __shared__ __align__(16) char smraw[35072];
  int i = blockIdx.x;
  int b = i >> 5, sl = i & 31;   // 32 batches x 32 slots
  int t = threadIdx.x;

  // ---- P1a: svm slice (128 l per block, all 64 channels) ----
  {
    float* tmp = (float*)smraw;                       // 128 floats
    float (*sred)[8] = (float(*)[8])(smraw + 512);    // [2][8]
    int lt = t & 127, ch = t >> 7;
    int l = sl * 128 + lt;
    const float* xb = x + (size_t)b * CN * LN + l;
    float acc = 0.f;
#pragma unroll
    for (int cc = 0; cc < 32; cc++) {
      float v = xb[(size_t)(ch * 32 + cc) * LN];
      acc = fmaf(v, v, acc);
    }
    if (ch == 1) tmp[lt] = acc;
    __syncthreads();
    if (ch == 0) {
      acc += tmp[lt];
      float svm = sqrtf(acc);
      ws[OFF_SVMBUF + (size_t)b * LN + l] = svm;
      const int third = LN / 3;     // 1365
      float vS = svm, vS2 = svm * svm;
      float vS2H  = (l >= LN/2) ? svm : 0.f;
      float vS2H2 = (l >= LN/2) ? svm * svm : 0.f;
      float vPRE  = (l < third) ? svm : 0.f;
      float vPOST = (l >= 2*third) ? svm : 0.f;
      float vMX = svm;
      float vMID = (l >= third && l < 2*third) ? svm : 0.f;
      for (int off = 32; off > 0; off >>= 1) {
        vS += __shfl_down(vS, off); vS2 += __shfl_down(vS2, off);
        vS2H += __shfl_down(vS2H, off); vS2H2 += __shfl_down(vS2H2, off);
        vPRE += __shfl_down(vPRE, off); vPOST += __shfl_down(vPOST, off);
        vMX = fmaxf(vMX, __shfl_down(vMX, off));
        vMID = fmaxf(vMID, __shfl_down(vMID, off));
      }
      if ((t & 63) == 0) {
        int w = t >> 6;
        sred[w][0]=vS; sred[w][1]=vS2; sred[w][2]=vMX; sred[w][3]=vS2H;
        sred[w][4]=vS2H2; sred[w][5]=vPRE; sred[w][6]=vMID; sred[w][7]=vPOST;
      }
    }
    __syncthreads();
    if (t == 0) {
      float* sp = ws + OFF_SVMST_PART + (size_t)(b * 32 + sl) * 8;
      sp[0]=sred[0][0]+sred[1][0];
      sp[1]=sred[0][1]+sred[1][1];
      sp[2]=fmaxf(sred[0][2],sred[1][2]);
      sp[3]=sred[0][3]+sred[1][3];
      sp[4]=sred[0][4]+sred[1][4];
      sp[5]=sred[0][5]+sred[1][5];
      sp[6]=fmaxf(sred[0][6],sred[1][6]);
      sp[7]=sred[0][7]+sred[1][7];
    }
    __syncthreads();   // before FFT overwrites smraw
  }

  // ---- P1b: FFT + fused row scans ----
  {
    const float* r0 = x + ((size_t)b * CN + 2 * sl) * LN;
    const float* r1 = r0 + LN;
    float2* z = (float2*)smraw;                        // FP(4096) float2 < 34816 B
    float (*sred8)[8] = (float(*)[8])(smraw + 34816);  // [4][8] scan partials
    float s0 = 0.f, jm0 = 0.f, jr0 = 0.f; int zc0 = 0;
    float s1v = 0.f, jm1 = 0.f, jr1 = 0.f; int zc1 = 0;
#pragma unroll
    for (int k = 0; k < 4; k++) {
      int n4 = (k * 256 + t) * 4;
      float4 a = *(const float4*)(r0 + n4);
      float4 c = *(const float4*)(r1 + n4);
      float a4 = __shfl_down(a.x, 1), a5 = __shfl_down(a.y, 1);
      float c4 = __shfl_down(c.x, 1), c5 = __shfl_down(c.y, 1);
      if ((t & 63) == 63) {
        a4 = (n4 + 4 < LN) ? r0[n4 + 4] : 0.f;
        a5 = (n4 + 5 < LN) ? r0[n4 + 5] : 0.f;
        c4 = (n4 + 4 < LN) ? r1[n4 + 4] : 0.f;
        c5 = (n4 + 5 < LN) ? r1[n4 + 5] : 0.f;
      }
      bool nl = (n4 + 4 < LN);
      s0 += a.x + a.y + a.z + a.w;
      jm0 = fmaxf(jm0, fmaxf(fmaxf(fabsf(a.y-a.x), fabsf(a.z-a.y)), fabsf(a.w-a.z)));
      zc0 += (a.x*a.y < 0.f) + (a.y*a.z < 0.f) + (a.z*a.w < 0.f);
      jr0 = fmaxf(jr0, fmaxf(fabsf(a.z - 2.f*a.y + a.x), fabsf(a.w - 2.f*a.z + a.y)));
      if (nl) {
        jm0 = fmaxf(jm0, fabsf(a4 - a.w));
        zc0 += (a.w * a4 < 0.f);
        jr0 = fmaxf(jr0, fmaxf(fabsf(a4 - 2.f*a.w + a.z), fabsf(a5 - 2.f*a4 + a.w)));
      }
      s1v += c.x + c.y + c.z + c.w;
      jm1 = fmaxf(jm1, fmaxf(fmaxf(fabsf(c.y-c.x), fabsf(c.z-c.y)), fabsf(c.w-c.z)));
      zc1 += (c.x*c.y < 0.f) + (c.y*c.z < 0.f) + (c.z*c.w < 0.f);
      jr1 = fmaxf(jr1, fmaxf(fabsf(c.z - 2.f*c.y + c.x), fabsf(c.w - 2.f*c.z + c.y)));
      if (nl) {
        jm1 = fmaxf(jm1, fabsf(c4 - c.w));
        zc1 += (c.w * c4 < 0.f);
        jr1 = fmaxf(jr1, fmaxf(fabsf(c4 - 2.f*c.w + c.z), fabsf(c5 - 2.f*c4 + c.w)));
      }
      float ar[4] = {a.x, a.y, a.z, a.w}, crr[4] = {c.x, c.y, c.z, c.w};
#pragma unroll
      for (int q = 0; q < 4; q++) {
        unsigned n = (unsigned)(n4 + q);
        unsigned br = __brev(n) >> 20;
        unsigned dr = ((br & 0x555u) << 1) | ((br & 0xAAAu) >> 1);
        z[FP(dr)] = make_float2(ar[q], crr[q]);
      }
    }
    for (int off = 32; off > 0; off >>= 1) {
      s0 += __shfl_down(s0, off); jm0 = fmaxf(jm0, __shfl_down(jm0, off));
      jr0 = fmaxf(jr0, __shfl_down(jr0, off)); zc0 += __shfl_down(zc0, off);
      s1v += __shfl_down(s1v, off); jm1 = fmaxf(jm1, __shfl_down(jm1, off));
      jr1 = fmaxf(jr1, __shfl_down(jr1, off)); zc1 += __shfl_down(zc1, off);
    }
    if ((t & 63) == 0) {
      int w = t >> 6;
      sred8[w][0]=s0; sred8[w][1]=jm0; sred8[w][2]=jr0; sred8[w][3]=(float)zc0;
      sred8[w][4]=s1v; sred8[w][5]=jm1; sred8[w][6]=jr1; sred8[w][7]=(float)zc1;
    }
    __syncthreads();
    if (t == 0) {
      int bc0 = b * CN + 2 * sl;
      float S0=0,J0=0,JR0=0,Z0=0,S1=0,J1=0,JR1=0,Z1=0;
      for (int w = 0; w < 4; w++) {
        S0 += sred8[w][0]; J0 = fmaxf(J0, sred8[w][1]); JR0 = fmaxf(JR0, sred8[w][2]); Z0 += sred8[w][3];
        S1 += sred8[w][4]; J1 = fmaxf(J1, sred8[w][5]); JR1 = fmaxf(JR1, sred8[w][6]); Z1 += sred8[w][7];
      }
      ws[OFF_CHAN_SUM + bc0]       = S0;           ws[OFF_CHAN_SUM + bc0 + 1]   = S1;
      ws[OFF_CHAN_JERK + bc0]      = J0 * 50.f;    ws[OFF_CHAN_JERK + bc0 + 1]  = J1 * 50.f;
      ws[OFF_CHAN_JRATE + bc0]     = JR0 * 2500.f; ws[OFF_CHAN_JRATE + bc0 + 1] = JR1 * 2500.f;
      ws[OFF_CHAN_ZCR + bc0]       = Z0;           ws[OFF_CHAN_ZCR + bc0 + 1]   = Z1;
    }
    const float c8r[4] = { 1.f, 0.92387953251f, 0.70710678119f, 0.38268343236f };
    const float c8i[4] = { 0.f, -0.38268343236f, -0.70710678119f, -0.92387953251f };
#pragma unroll
    for (int p = 0; p < 3; p++) {
      const int H = (p == 0) ? 1 : (p == 1) ? 16 : 256;
      int rr = t & (H - 1);
      int B = ((t / H) * 16 * H) + rr;
      float2 E[16];
#pragma unroll
      for (int q = 0; q < 16; q++) E[q] = z[FP(B + q * H)];
      float su, cu;
      sincospif((float)rr / (8.0f * (float)H), &su, &cu);
      float ur = cu, ui = -su;
      float u2r = ur*ur - ui*ui, u2i = 2.f*ur*ui;
      float w1r = u2r*u2r - u2i*u2i, w1i = 2.f*u2r*u2i;      // u^4
      float w2r = w1r*w1r - w1i*w1i, w2i = 2.f*w1r*w1i;       // u^8
      float w3r = w2r*w1r - w2i*w1i, w3i = w2r*w1i + w2i*w1r; // u^12
#pragma unroll
      for (int m = 0; m < 4; m++)
        bfly4(E[4*m], E[4*m+1], E[4*m+2], E[4*m+3], w1r, w1i, w2r, w2i, w3r, w3i);
#pragma unroll
      for (int m = 0; m < 4; m++) {
        float W1r = ur*c8r[m] - ui*c8i[m];
        float W1i = ur*c8i[m] + ui*c8r[m];
        float W2r = W1r*W1r - W1i*W1i, W2i = 2.f*W1r*W1i;
        float W3r = W2r*W1r - W2i*W1i, W3i = W2r*W1i + W2i*W1r;
        bfly4(E[m], E[m+4], E[m+8], E[m+12], W1r, W1i, W2r, W2i, W3r, W3i);
      }
#pragma unroll
      for (int q = 0; q < 16; q++) z[FP(B + q * H)] = E[q];
      __syncthreads();
    }
    float tot = 0.f, cen = 0.f, hi = 0.f;
    for (int k = t; k <= LN / 2; k += NTH) {
      float p;
      if (k == 0 || k == LN / 2) {
        float2 v = z[FP(k)];
        p = v.x * v.x + v.y * v.y;
      } else {
        float2 zk = z[FP(k)], zn = z[FP(LN - k)];
        float a1 = zk.x + zn.x, a2 = zk.y - zn.y, a3 = zk.y + zn.y, a4v = zk.x - zn.x;
        p = 0.25f * (a1*a1 + a2*a2 + a3*a3 + a4v*a4v);
      }
      p *= (1.0f / LN);
      tot += p;
      cen += p * ((float)k * (1.0f / (LN / 2)));
      if (k >= 820) hi += p;
    }
    for (int off = 32; off > 0; off >>= 1) {
      tot += __shfl_down(tot, off);
      cen += __shfl_down(cen, off);
      hi  += __shfl_down(hi, off);
    }
    float (*redS)[4] = (float(*)[4])(smraw + 34816);
    if ((t & 63) == 0) { int w = t >> 6; redS[0][w] = tot; redS[1][w] = cen; redS[2][w] = hi; }
    __syncthreads();
    if (t == 0) {
      float* sp = ws + OFF_SPEC_PART + (size_t)(b * 32 + sl) * 3;
      sp[0] = redS[0][0]+redS[0][1]+redS[0][2]+redS[0][3];
      sp[1] = redS[1][0]+redS[1][1]+redS[1][2]+redS[1][3];
      sp[2] = redS[2][0]+redS[2][1]+redS[2][2]+redS[2][3];
    }
  }
}

// ================= k2: gate (redundant per block) + eff weights + conv (1 row/block, 2048 blocks) =================
__global__ __launch_bounds__(NTH) void k2_conv(
    const float* __restrict__ x,
    const float* __restrict__ dw7, const float* __restrict__ dw15,
    const float* __restrict__ dw31, const float* __restrict__ dw63,
    const float* __restrict__ bn_g, const float* __restrict__ bn_b,
    const float* __restrict__ bn_m, const float* __restrict__ bn_v,
    const float* __restrict__ comp_w1, const float* __restrict__ comp_b1,
    const float* __restrict__ comp_w2, const float* __restrict__ comp_b2,
    const float* __restrict__ pn_g, const float* __restrict__ pn_b,
    const float* __restrict__ pn_m, const float* __restrict__ pn_v,
    const float* __restrict__ pe_w1, const float* __restrict__ pe_b1,
    const float* __restrict__ pe_w2, const float* __restrict__ pe_b2,
    const float* __restrict__ pg_w, const float* __restrict__ pg_b,
    const float* __restrict__ temperature,
    float* __restrict__ ws)
{
  int i = blockIdx.x;
  int b = i >> 6, c = i & 63;      // 32 batches x 64 channels
  int t = threadIdx.x;
  __shared__ float sp8[32][8];
  __shared__ float sp3[32][3];
  __shared__ float stv[10];
  __shared__ float bc2[2];
  __shared__ float xm[64], h[64], pf[12], pe1v[32], pe2v[32], lgts[4], swts[4];
  __shared__ int ri[3][4], cnts[3];
  __shared__ float cwt[64];
  __shared__ float cbias;
  __shared__ double rda[2][4];

  // ---- gate (round-2 structure, verbatim; redundant per block) ----
  if (t < 32) {
    const float* p = ws + OFF_SVMST_PART + (size_t)(b * 32 + t) * 8;
#pragma unroll
    for (int q = 0; q < 8; q++) sp8[t][q] = p[q];
  }
  if (t >= 32 && t < 64) {
    int q = t - 32;
    const float* p = ws + OFF_SPEC_PART + (size_t)(b * 32 + q) * 3;
    sp3[q][0] = p[0]; sp3[q][1] = p[1]; sp3[q][2] = p[2];
  }
  __syncthreads();
  if (t == 0) {
    float S=0,S2=0,MX=-1e30f,S2H=0,S2H2=0,PRE=0,MID=-1e30f,POST=0;
    for (int q = 0; q < 32; q++) {
      S += sp8[q][0]; S2 += sp8[q][1]; MX = fmaxf(MX, sp8[q][2]);
      S2H += sp8[q][3]; S2H2 += sp8[q][4]; PRE += sp8[q][5];
      MID = fmaxf(MID, sp8[q][6]); POST += sp8[q][7];
    }
    float tt=0,ce=0,hh=0;
    for (int q = 0; q < 32; q++) { tt += sp3[q][0]; ce += sp3[q][1]; hh += sp3[q][2]; }
    stv[0]=S; stv[1]=S2; stv[2]=MX; stv[3]=S2H; stv[4]=S2H2;
    stv[5]=PRE; stv[6]=MID; stv[7]=POST; stv[8]=ce/(tt+1e-6f); stv[9]=hh/(tt+1e-6f);
    float mean = S * (1.f / LN);
    float var = (S2 - S * S * (1.f / LN)) * (1.f / (LN - 1));
    var = fmaxf(var, 0.f);
    bc2[0] = mean;
    bc2[1] = sqrtf(var) + 1e-6f;
  }
  __syncthreads();
  float mean = bc2[0], stde = bc2[1];
  float thr2 = mean + 2.f * stde, thr3 = mean + 3.f * stde, thrf = mean - stde;
  const float* svm = ws + OFF_SVMBUF + (size_t)b * LN;
  int cc2 = 0, cc3 = 0, ccf = 0;
  for (int l = t; l < LN; l += NTH) {
    float v = svm[l];
    cc2 += (v > thr2); cc3 += (v > thr3); ccf += (v < thrf);
  }
  for (int off = 32; off > 0; off >>= 1) {
    cc2 += __shfl_down(cc2, off); cc3 += __shfl_down(cc3, off); ccf += __shfl_down(ccf, off);
  }
  {
    int w = t >> 6;
    if ((t & 63) == 0) { ri[0][w] = cc2; ri[1][w] = cc3; ri[2][w] = ccf; }
  }
  float j = 0.f, jr = 0.f, zz = 0.f;
  if (t < 64) {
    xm[t] = ws[OFF_CHAN_SUM + b * 64 + t] * (1.0f / LN);
    j  = ws[OFF_CHAN_JERK + b * 64 + t];
    jr = ws[OFF_CHAN_JRATE + b * 64 + t];
    zz = ws[OFF_CHAN_ZCR + b * 64 + t];
    for (int off = 32; off > 0; off >>= 1) {
      j += __shfl_down(j, off); jr += __shfl_down(jr, off); zz += __shfl_down(zz, off);
    }
  }
  __syncthreads();
  if (t == 0) {
    cnts[0] = ri[0][0]+ri[0][1]+ri[0][2]+ri[0][3];
    cnts[1] = ri[1][0]+ri[1][1]+ri[1][2]+ri[1][3];
    cnts[2] = ri[2][0]+ri[2][1]+ri[2][2]+ri[2][3];
    const int third = LN / 3;
    float S2H = stv[3], S2H2 = stv[4];
    float n2 = (float)(LN / 2);
    float var2 = (S2H2 - S2H * S2H / n2) / (n2 - 1.f);
    var2 = fmaxf(var2, 0.f);
    float post_still = tanhf(1.f / (sqrtf(var2) + 1e-6f));
    float pre_mean = stv[5] / (float)third;
    float post_mean = stv[7] / (float)(LN - 2 * third);
    float pk = stv[6];
    float fp2 = fmaxf(pk - pre_mean, 0.f) + fmaxf(pk - post_mean, 0.f);
    fp2 = fp2 / (fabsf(pk) + 1e-6f);
    pf[0] = stv[2];
    pf[1] = mean;
    pf[2] = j * (1.f / 64);
    pf[3] = jr * (1.f / 64);
    pf[4] = (zz * (1.f / 64)) * (1.f / LN);
    pf[5] = (float)cnts[0] / LN;
    pf[6] = (float)cnts[1] / LN;
    pf[7] = post_still;
    pf[8] = (float)cnts[2] / LN;
    pf[9] = stv[8];
    pf[10] = stv[9];
    pf[11] = fp2;
  }
  __syncthreads();
  if (t < 12) pf[t] = (pf[t] - pn_m[t]) * rsqrtf(pn_v[t] + 1e-5f) * pn_g[t] + pn_b[t];
  __syncthreads();
  if (t < 64) {
    float hv = comp_b1[t];
    for (int q = 0; q < 64; q++) hv = fmaf(xm[q], comp_w1[q * 64 + t], hv);
    h[t] = fmaxf(hv, 0.f);
  }
  if (t < 32) {
    float v = pe_b1[t];
    for (int q = 0; q < 12; q++) v = fmaf(pf[q], pe_w1[q * 32 + t], v);
    pe1v[t] = fmaxf(v, 0.f);
  }
  __syncthreads();
  if (t < 32) {
    float v = pe_b2[t];
    for (int q = 0; q < 32; q++) v = fmaf(pe1v[q], pe_w2[q * 32 + t], v);
    pe2v[t] = fmaxf(v, 0.f);
  }
  __syncthreads();
  if (t < 4) {
    float v = comp_b2[t];
    for (int q = 0; q < 64; q++) v = fmaf(h[q], comp_w2[q * 4 + t], v);
    float g = pg_b[t];
    for (int q = 0; q < 32; q++) g = fmaf(pe2v[q], pg_w[q * 4 + t], g);
    g = 1.f / (1.f + expf(-g));
    float temp = fmaxf(temperature[0], 0.1f);
    lgts[t] = v * g / temp;
  }
  __syncthreads();
  if (t < 4) {
    float m = fmaxf(fmaxf(lgts[0], lgts[1]), fmaxf(lgts[2], lgts[3]));
    float den = expf(lgts[0]-m) + expf(lgts[1]-m) + expf(lgts[2]-m) + expf(lgts[3]-m);
    swts[t] = expf(lgts[t] - m) / den;
  }
  __syncthreads();

  // ---- eff weights for this block's single channel ----
  if (t < 64) {
    int tau = t;
    float w0 = swts[0], w1 = swts[1], w2 = swts[2], w3 = swts[3];
    float sc0 = bn_g[0*64+c] * rsqrtf(bn_v[0*64+c] + 1e-5f);
    float sc1 = bn_g[1*64+c] * rsqrtf(bn_v[1*64+c] + 1e-5f);
    float sc2 = bn_g[2*64+c] * rsqrtf(bn_v[2*64+c] + 1e-5f);
    float sc3 = bn_g[3*64+c] * rsqrtf(bn_v[3*64+c] + 1e-5f);
    float a0 = w0*sc0, a1 = w1*sc1, a2 = w2*sc2, a3 = w3*sc3;
    if (tau == 0) {
      float o0 = bn_b[0*64+c] - bn_m[0*64+c] * sc0;
      float o1 = bn_b[1*64+c] - bn_m[1*64+c] * sc1;
      float o2 = bn_b[2*64+c] - bn_m[2*64+c] * sc2;
      float o3 = bn_b[3*64+c] - bn_m[3*64+c] * sc3;
      cbias = w0*o0 + w1*o1 + w2*o2 + w3*o3;
    }
    float v = 0.f;
    if (tau < 63) {
      v = a3 * dw63[c * 63 + tau];
      int i7 = tau - 28;  if (i7 >= 0 && i7 < 7)    v = fmaf(a0, dw7[c * 7 + i7], v);
      int i15 = tau - 24; if (i15 >= 0 && i15 < 15) v = fmaf(a1, dw15[c * 15 + i15], v);
      int i31 = tau - 16; if (i31 >= 0 && i31 < 31) v = fmaf(a2, dw31[c * 31 + i31], v);
    }
    cwt[tau] = v;
  }
  __syncthreads();

  // ---- conv: single row, 5-register sliding window; bf16 output to ws ----
  {
    const float* row = x + ((size_t)b * CN + c) * LN;
    float bias = cbias;
    int l0 = t * 16, g0 = l0 - 32;
    float4 R0 = ldmask(row, g0);
    float4 R1 = ldmask(row, g0 + 4);
    float4 R2 = ldmask(row, g0 + 8);
    float4 R3 = ldmask(row, g0 + 12);
    float4 R4 = ldmask(row, g0 + 16);
    float acc[16];
#pragma unroll
    for (int q = 0; q < 16; q++) acc[q] = bias;
#pragma unroll
    for (int g = 0; g < 16; g++) {
      float w0 = cwt[4*g], w1 = cwt[4*g+1], w2 = cwt[4*g+2], w3 = cwt[4*g+3];
      F16(w0, R0.y,R0.z,R0.w,R1.x,R1.y,R1.z,R1.w,R2.x,R2.y,R2.z,R2.w,R3.x,R3.y,R3.z,R3.w,R4.x)
      F16(w1, R0.z,R0.w,R1.x,R1.y,R1.z,R1.w,R2.x,R2.y,R2.z,R2.w,R3.x,R3.y,R3.z,R3.w,R4.x,R4.y)
      F16(w2, R0.w,R1.x,R1.y,R1.z,R1.w,R2.x,R2.y,R2.z,R2.w,R3.x,R3.y,R3.z,R3.w,R4.x,R4.y,R4.z)
      F16(w3, R1.x,R1.y,R1.z,R1.w,R2.x,R2.y,R2.z,R2.w,R3.x,R3.y,R3.z,R3.w,R4.x,R4.y,R4.z,R4.w)
      if (g < 15) {
        R0 = R1; R1 = R2; R2 = R3; R3 = R4;
        R4 = ldmask(row, g0 + 4 * (g + 5));
      }
    }
    double ls = 0, ls2 = 0;
#pragma unroll
    for (int q = 0; q < 16; q++) { float v = acc[q]; ls += v; ls2 += (double)v * (double)v; }
    for (int off = 32; off > 0; off >>= 1) {
      ls += __shfl_down(ls, off);
      ls2 += __shfl_down(ls2, off);
    }
    int w = t >> 6;
    if ((t & 63) == 0) { rda[0][w] = ls; rda[1][w] = ls2; }
    // bf16 pack: 16 values -> 8 u32 -> 2 uint4 stores (32 B/thread, contiguous)
    unsigned short* mdst = (unsigned short*)(ws + OFF_MIX) + ((size_t)(b * CN + c)) * LN + l0;
    unsigned pk[8];
#pragma unroll
    for (int q = 0; q < 8; q++)
      pk[q] = (unsigned)f2bf(acc[2*q]) | ((unsigned)f2bf(acc[2*q+1]) << 16);
    uint4 v0 = make_uint4(pk[0], pk[1], pk[2], pk[3]);
    uint4 v1 = make_uint4(pk[4], pk[5], pk[6], pk[7]);
    *(uint4*)(mdst) = v0;
    *(uint4*)(mdst + 8) = v1;
    __syncthreads();
    if (t == 0) {
      double* gp = (double*)(ws + OFF_GNP);
      gp[2 * (b * CN + c) + 0] = rda[0][0]+rda[0][1]+rda[0][2]+rda[0][3];
      gp[2 * (b * CN + c) + 1] = rda[1][0]+rda[1][1]+rda[1][2]+rda[1][3];
    }
  }
}

// ================= k3: GN + GELU + proj + residual (2048 blocks, 64-l tile, no Wt LDS) =================
#define PROJ4(ACC, WV) \
  ACC.x = fmaf(WV.x, a0.x, ACC.x); ACC.y = fmaf(WV.x, a0.y, ACC.y); ACC.z = fmaf(WV.x, a0.z, ACC.z); ACC.w = fmaf(WV.x, a0.w, ACC.w); \
  ACC.x = fmaf(WV.y, a1.x, ACC.x); ACC.y = fmaf(WV.y, a1.y, ACC.y); ACC.z = fmaf(WV.y, a1.z, ACC.z); ACC.w = fmaf(WV.y, a1.w, ACC.w); \
  ACC.x = fmaf(WV.z, a2.x, ACC.x); ACC.y = fmaf(WV.z, a2.y, ACC.y); ACC.z = fmaf(WV.z, a2.z, ACC.z); ACC.w = fmaf(WV.z, a2.w, ACC.w); \
  ACC.x = fmaf(WV.w, a3.x, ACC.x); ACC.y = fmaf(WV.w, a3.y, ACC.y); ACC.z = fmaf(WV.w, a3.z, ACC.z); ACC.w = fmaf(WV.w, a3.w, ACC.w);

__global__ __launch_bounds__(NTH) void k3_final(const float* __restrict__ x,
    const float* __restrict__ proj_w, const float* __restrict__ proj_b,
    const float* __restrict__ gn_g, const float* __restrict__ gn_b,
    const float* __restrict__ res_scale,
    const float* __restrict__ ws, float* out) {
  __shared__ __align__(16) char smraw[16456];
  int i = blockIdx.x;
  int b = i >> 6, sl = i & 63;     // 32 batches x 64 slots of 64 l
  int t = threadIdx.x;
  float* actS = (float*)smraw;                      // 64x64 = 16384 B
  double (*rg)[4] = (double(*)[4])(smraw + 16384);  // 64 B
  float* bcst = (float*)(smraw + 16448);            // 2
  const double* gp = (const double*)(ws + OFF_GNP) + (size_t)b * CN * 2;
  double g1 = 0, g2 = 0;
  if (t < CN) { g1 = gp[2*t]; g2 = gp[2*t+1]; }
  for (int off = 32; off > 0; off >>= 1) { g1 += __shfl_down(g1, off); g2 += __shfl_down(g2, off); }
  {
    int w = t >> 6;
    if ((t & 63) == 0) { rg[0][w] = g1; rg[1][w] = g2; }
  }
  __syncthreads();
  if (t == 0) {
    double S1 = rg[0][0]+rg[0][1]+rg[0][2]+rg[0][3];
    double S2 = rg[1][0]+rg[1][1]+rg[1][2]+rg[1][3];
    const double NN = 64.0 * 4096.0;
    double mud = S1 / NN;
    bcst[0] = (float)mud;
    bcst[1] = rsqrtf((float)(S2 / NN - mud * mud) + 1e-5f);
  }
  __syncthreads();
  float mu = bcst[0], rstd = bcst[1];
  float rsv = res_scale[0];
  const unsigned short* mx = (const unsigned short*)(ws + OFF_MIX) + (size_t)b * CN * LN;
  const float* xb = x + (size_t)b * CN * LN;
  float* ob = out + (size_t)b * CN * LN;
  int lbase = sl * 64;
  // GN + GELU into LDS (bf16 ingest, 2 l per iteration)
  for (int q = t; q < 2048; q += NTH) {
    int c = q >> 5, lp = (q & 31) * 2;
    unsigned v2 = *(const unsigned*)&mx[(size_t)c * LN + lbase + lp];
    float f0 = __uint_as_float(v2 << 16);
    float f1 = __uint_as_float(v2 & 0xFFFF0000u);
    float gA = (f0 - mu) * rstd * gn_g[c] + gn_b[c];
    float gB = (f1 - mu) * rstd * gn_g[c] + gn_b[c];
    actS[c * 64 + lp]     = 0.5f * gA * (1.f + erff(gA * 0.70710678118654752f));
    actS[c * 64 + lp + 1] = 0.5f * gB * (1.f + erff(gB * 0.70710678118654752f));
  }
  __syncthreads();
  // proj: each thread covers 4 o (og..og+3) x 4 l (lq*4..+3); weights from global (L1-broadcast)
  int lq = t & 15, og = (t >> 4) * 4;
  float4 acc4[4];
#pragma unroll
  for (int oo = 0; oo < 4; oo++) acc4[oo] = make_float4(0.f, 0.f, 0.f, 0.f);
  for (int c4 = 0; c4 < 16; c4++) {
    int cb = c4 * 4;
    float4 a0 = *(const float4*)&actS[(cb + 0) * 64 + lq * 4];
    float4 a1 = *(const float4*)&actS[(cb + 1) * 64 + lq * 4];
    float4 a2 = *(const float4*)&actS[(cb + 2) * 64 + lq * 4];
    float4 a3 = *(const float4*)&actS[(cb + 3) * 64 + lq * 4];
    float4 w0v = *(const float4*)&proj_w[(og + 0) * 64 + cb];
    float4 w1v = *(const float4*)&proj_w[(og + 1) * 64 + cb];
    float4 w2v = *(const float4*)&proj_w[(og + 2) * 64 + cb];
    float4 w3v = *(const float4*)&proj_w[(og + 3) * 64 + cb];
    PROJ4(acc4[0], w0v)
    PROJ4(acc4[1], w1v)
    PROJ4(acc4[2], w2v)
    PROJ4(acc4[3], w3v)
  }
#pragma unroll
  for (int oo = 0; oo < 4; oo++) {
    int o = og + oo;
    float pb = proj_b[o];
    size_t base = (size_t)o * LN + lbase + lq * 4;
    float4 xv = *(const float4*)&xb[base];
    float4 rr2;
    rr2.x = xv.x + rsv * (acc4[oo].x + pb);
    rr2.y = xv.y + rsv * (acc4[oo].y + pb);
    rr2.z = xv.z + rsv * (acc4[oo].z + pb);
    rr2.w = xv.w + rsv * (acc4[oo].w + pb);
    *(float4*)&ob[base] = rr2;
  }
}

extern "C" void kernel_launch(void* const* d_in, const int* in_sizes, int n_in,
                              void* d_out, int out_size, void* d_ws, size_t ws_size,
                              hipStream_t stream) {
  const float* x        = (const float*)d_in[0];
  const float* dw7      = (const float*)d_in[1];
  const float* dw15     = (const float*)d_in[2];
  const float* dw31     = (const float*)d_in[3];
  const float* dw63     = (const float*)d_in[4];
  const float* bn_g     = (const float*)d_in[5];
  const float* bn_b     = (const float*)d_in[6];
  const float* bn_m     = (const float*)d_in[7];
  const float* bn_v     = (const float*)d_in[8];
  const float* comp_w1  = (const float*)d_in[9];
  const float* comp_b1  = (const float*)d_in[10];
  const float* comp_w2  = (const float*)d_in[11];
  const float* comp_b2  = (const float*)d_in[12];
  const float* pn_g     = (const float*)d_in[13];
  const float* pn_b     = (const float*)d_in[14];
  const float* pn_m     = (const float*)d_in[15];
  const float* pn_v     = (const float*)d_in[16];
  const float* pe_w1    = (const float*)d_in[17];
  const float* pe_b1    = (const float*)d_in[18];
  const float* pe_w2    = (const float*)d_in[19];
  const float* pe_b2    = (const float*)d_in[20];
  const float* pg_w     = (const float*)d_in[21];
  const float* pg_b     = (const float*)d_in[22];
  const float* temperature = (const float*)d_in[23];
  const float* gn_g     = (const float*)d_in[24];
  const float* gn_b     = (const float*)d_in[25];
  const float* proj_w   = (const float*)d_in[26];
  const float* proj_b   = (const float*)d_in[27];
  const float* res_scale= (const float*)d_in[28];
  float* ws = (float*)d_ws;
  float* out = (float*)d_out;

  hipLaunchKernelGGL(k1_spec, dim3(1024), dim3(NTH), 0, stream, x, ws);
  hipLaunchKernelGGL(k2_conv, dim3(2048), dim3(NTH), 0, stream,
                     x, dw7, dw15, dw31, dw63, bn_g, bn_b, bn_m, bn_v,
                     comp_w1, comp_b1, comp_w2, comp_b2,
                     pn_g, pn_b, pn_m, pn_v, pe_w1, pe_b1, pe_w2, pe_b2,
                     pg_w, pg_b, temperature, ws);
  hipLaunchKernelGGL(k3_final, dim3(2048), dim3(NTH), 0, stream,
                     x, proj_w, proj_b, gn_g, gn_b, res_scale, ws, out);
}